// Round 3
// baseline (1456.232 us; speedup 1.0000x reference)
//
#include <hip/hip_runtime.h>

typedef unsigned short u16;
using f16x8 = __attribute__((ext_vector_type(8))) _Float16;  // 8 fp16 (4 VGPRs)
using f32x4 = __attribute__((ext_vector_type(4))) float;

#define V_N 16384
#define M_N 32768

__device__ __forceinline__ float h2f(u16 u) {
  _Float16 h; __builtin_memcpy(&h, &u, 2); return (float)h;
}
__device__ __forceinline__ u16 f2h(float f) {
  _Float16 h = (_Float16)f; u16 u; __builtin_memcpy(&u, &h, 2); return u;
}

// lgkm-only barrier: ds ops drained, vmcnt (in-flight gathers) crosses freely
__device__ __forceinline__ void wgbar() {
  asm volatile("s_waitcnt lgkmcnt(0)" ::: "memory");
  __builtin_amdgcn_s_barrier();
  asm volatile("" ::: "memory");
}

// ---------- prep kernels ----------
// LDS-transpose weight permute: wp[o][t*256+c] = f2h(w[o][c*12+t])
__global__ __launch_bounds__(256) void perm2_k(const float* __restrict__ w, u16* __restrict__ wp) {
  __shared__ u16 l[3072];
  int o = blockIdx.x & 255, layer = blockIdx.x >> 8;
  int t = threadIdx.x;
  const float* src = w + ((size_t)layer * 256 + o) * 3072;
  u16* dst = wp + ((size_t)layer * 256 + o) * 3072;
  float2 v[6];
  #pragma unroll
  for (int q = 0; q < 6; ++q) v[q] = *(const float2*)(src + t * 12 + q * 2);
  const float* vf = (const float*)v;
  #pragma unroll
  for (int m = 0; m < 12; ++m) l[m * 256 + t] = f2h(vf[m]);   // c = t
  __syncthreads();
  unsigned* d32 = (unsigned*)dst;
  const unsigned* l32 = (const unsigned*)l;
  #pragma unroll
  for (int q = 0; q < 6; ++q) d32[t * 6 + q] = l32[t * 6 + q];
}

// flat f32 -> fp16 convert
__global__ __launch_bounds__(256) void cvt_k(const float* __restrict__ w, u16* __restrict__ wb, int n) {
  int i = blockIdx.x * 256 + threadIdx.x;
  if (i < n) wb[i] = f2h(w[i]);
}

// per-batch SE-scale fold into weights: o[b][i] = w[i] * sig[b][channel]
// sel=255: enc conv (all K scaled). sel=511: skip (only k>=256 scaled).
__global__ __launch_bounds__(256) void wscale_k(const u16* __restrict__ w, const float* __restrict__ sig,
                                                u16* __restrict__ o, int n, int sel) {
  int i = blockIdx.x * 256 + threadIdx.x;
  if (i >= n) return;
  float wv = h2f(w[i]);
  int k = i & sel;
  int c = k & 255;
  #pragma unroll
  for (int b = 0; b < 2; ++b) {
    float s = (sel == 511 && k < 256) ? 1.f : sig[b * 256 + c];
    o[(long)b * n + i] = f2h(wv * s);
  }
}

// ---------- encoder block 0 conv (C_in=3, K=36), f32 in -> fp16 out ----------
__global__ __launch_bounds__(256) void enc0_k(const float* __restrict__ verts, const int* __restrict__ sp,
                                              const float* __restrict__ w0, u16* __restrict__ y) {
  __shared__ float xs[32][36];
  int t = threadIdx.x;
  int r0 = blockIdx.x * 32;
  for (int s = t; s < 32 * 12; s += 256) {
    int row = s / 12, tt = s - row * 12;
    int gr = r0 + row;
    int b = gr >> 14, v = gr & (V_N - 1);
    int j = sp[tt * V_N + v];
    const float* p = verts + ((long)b * V_N + j) * 3;
    xs[row][tt]      = p[0];
    xs[row][12 + tt] = p[1];
    xs[row][24 + tt] = p[2];
  }
  __syncthreads();
  float w[36];
  #pragma unroll
  for (int k = 0; k < 36; ++k) w[k] = w0[t * 36 + k];
  for (int row = 0; row < 32; ++row) {
    float a = 0.f;
    #pragma unroll
    for (int k = 0; k < 36; ++k) a += w[k] * xs[row][k];
    y[(long)(r0 + row) * 256 + t] = f2h(a);
  }
}

// ---------- MFMA GEMM: 64M x 256N tile, 512 thr, register-staged gather pipeline ----------
// T14 depth-2 pipeline: gathers go global->VGPR (per-lane dwordx4) 2 stages
// before their ds_write; wait is a precise register dependency (compiler emits
// counted vmcnt), so in-flight gathers cross the lgkm-only barriers. 3 rotating
// static register sets S0/S1/S2 (rule #20: static indexing). B-loads hoisted to
// stage top BEFORE gather-issue (sched_barrier fence) so waiting on B never
// retires younger gathers (in-order vmcnt).
// Per half-stage s: loadB(s) | fence | ds_write G[s+1] | issue G[s+3] | compute
// buf[s&1] | lgkm0+barrier.  2x16KB LDS, 2 blocks/CU, 4 waves/SIMD.
template<int CT>
__global__ __launch_bounds__(512, 4) void gemm3_k(
    const u16* __restrict__ P0, const u16* __restrict__ P1, int lda,
    const int* __restrict__ sp, int L,
    const u16* __restrict__ Wt, long wstride,
    u16* __restrict__ Yb, const float* __restrict__ bias, int Ostore,
    float* __restrict__ stats)
{
  constexpr int KC   = CT >> 5;          // k-chunks (32 elems) per tap
  constexpr int KCH  = KC >> 1;          // k-chunks per half-stage
  constexpr int HROW = CT >> 1;          // elems per half-row (= CT bytes)
  constexpr int CHT  = CT >> 4;          // 16B chunks per half-row
  constexpr int RSH  = (CHT == 16) ? 4 : 3;
  constexpr int CMSK = CHT - 1;
  constexpr int RPI  = 64 / CHT;         // rows per load-instr group
  constexpr int RW   = 8;                // rows per wave (64 rows / 8 waves)
  constexpr int QN   = (RW * CT) / 1024; // 16B loads per thread per half-stage (2 or 1)
  __shared__ __align__(16) u16 lA[2][64 * HROW];   // 2 x 16KB half-stage buffers
  const int tid  = threadIdx.x;
  const int wave = tid >> 6, lane = tid & 63;
  const int wn = wave * 32;              // N-split-8: 32 cols per wave
  const int lr = lane & 15, lq = lane >> 4;
  // XCD-aware bijective swizzle (nwg % 8 == 0 for all call sites)
  const int nwg = gridDim.x;
  const int wg = (blockIdx.x & 7) * (nwg >> 3) + (blockIdx.x >> 3);
  const int bm = wg * 64;
  const int batch = bm >> 14;
  const int vbase = bm & (V_N - 1);
  const int qrow = lane >> RSH;          // row within load group
  const int qchunk = lane & CMSK;        // 16B chunk within row
  const bool gat = (sp != nullptr);
  const long rowb = (long)batch * V_N;   // gather row base (rows)
  const u16* Pd1 = P1 ? P1 : P0;
  const u16* Wb = Wt + (long)batch * wstride;
  const int ldw = L * CT;

  // B fragment pointers (2 col-tiles of 16 per wave)
  const u16* bp[2];
  #pragma unroll
  for (int nt = 0; nt < 2; ++nt) bp[nt] = Wb + (long)(wn + nt * 16 + lr) * ldw + lq * 8;

  auto load_idx = [&](int tap) -> int {
    int v = 0;
    if (gat && tap < L && lane < RW) v = sp[(long)tap * V_N + vbase + wave * RW + lane];
    return v;
  };

  // issue gather for (tap, half) into register set G (global chunk linear)
  auto gissue = [&](uint4 (&G)[QN], int tap, int h, int idxreg) {
    const u16* src = gat ? P0 : (tap == 0 ? P0 : Pd1);
    #pragma unroll
    for (int q = 0; q < QN; ++q) {
      int rloc = wave * RW + q * RPI + qrow;
      long grow = gat ? (rowb + (long)__shfl(idxreg, q * RPI + qrow, 64))
                      : (long)(bm + rloc);
      G[q] = *(const uint4*)(src + grow * lda + h * HROW + qchunk * 8);
    }
  };

  // ds_write register set to XOR-swizzled LDS slots (read side unchanged)
  auto gwrite = [&](uint4 (&G)[QN], int sb) {
    u16* buf = lA[sb];
    #pragma unroll
    for (int q = 0; q < QN; ++q) {
      int rloc = wave * RW + q * RPI + qrow;
      *(uint4*)(buf + rloc * HROW + ((qchunk ^ (rloc & 7)) << 3)) = G[q];
    }
  };

  auto loadB = [&](int cb, f16x8 (&tB)[KCH * 2]) {
    #pragma unroll
    for (int kp = 0; kp < KCH; ++kp)
      #pragma unroll
      for (int nt = 0; nt < 2; ++nt)
        tB[kp * 2 + nt] = *(const f16x8*)(bp[nt] + (long)(cb + kp) * 32);
  };

  f32x4 acc[4][2];
  #pragma unroll
  for (int i = 0; i < 4; ++i)
    #pragma unroll
    for (int j = 0; j < 2; ++j) acc[i][j] = (f32x4){0.f, 0.f, 0.f, 0.f};

  auto compute = [&](int sb, const f16x8 (&tB)[KCH * 2]) {
    const u16* buf = lA[sb];
    #pragma unroll
    for (int kp = 0; kp < KCH; ++kp) {
      f16x8 a[4];
      #pragma unroll
      for (int mt = 0; mt < 4; ++mt) {
        int row = mt * 16 + lr;
        a[mt] = *(const f16x8*)(&buf[row * HROW + (((kp * 4 + lq) ^ (row & 7)) << 3)]);
      }
      #pragma unroll
      for (int mt = 0; mt < 4; ++mt)
        #pragma unroll
        for (int nt = 0; nt < 2; ++nt)
          acc[mt][nt] = __builtin_amdgcn_mfma_f32_16x16x32_f16(a[mt], tB[kp * 2 + nt], acc[mt][nt], 0, 0, 0);
    }
  };

  // ---- rotating gather register sets: G[k] lives in set k%3 ----
  uint4 S0[QN], S1[QN], S2[QN];
  int idx1, idx2;              // idx(l+1), idx(l+2) rolling
  {
    int idx0 = load_idx(0);
    idx1 = load_idx(1);
    idx2 = load_idx(2);
    gissue(S0, 0, 0, idx0);              // G[0]
    gissue(S1, 0, 1, idx0);              // G[1]
    if (L > 1) gissue(S2, 1, 0, idx1);   // G[2]
    gwrite(S0, 0);                       // waits S0 only (counted vmcnt keeps S1/S2)
    wgbar();
  }

  // body(l): stages s=2l (h0, buf0) and s=2l+1 (h1, buf1).
  // X = set (2l)%3, Y = (2l+1)%3, Z = (2l+2)%3.
  auto body = [&](int l, uint4 (&X)[QN], uint4 (&Y)[QN], uint4 (&Z)[QN]) {
    // ---- stage 2l ----
    f16x8 tB0[KCH * 2];
    loadB(l * KC, tB0);
    __builtin_amdgcn_sched_barrier(0);           // B issued before gathers (queue order)
    gwrite(Y, 1);                                // G[2l+1] -> buf1 (issued 2 stages ago)
    if (l + 1 < L) gissue(X, l + 1, 1, idx1);    // G[2l+3]
    int idx3 = load_idx(l + 3);
    compute(0, tB0);
    wgbar();
    // ---- stage 2l+1 ----
    f16x8 tB1[KCH * 2];
    loadB(l * KC + KCH, tB1);
    __builtin_amdgcn_sched_barrier(0);
    if (l + 1 < L) gwrite(Z, 0);                 // G[2l+2] -> buf0
    if (l + 2 < L) gissue(Y, l + 2, 0, idx2);    // G[2l+4]
    compute(1, tB1);
    wgbar();
    idx1 = idx2; idx2 = idx3;
  };

  for (int l = 0; l < L; l += 3) {
    body(l, S0, S1, S2);
    if (l + 1 < L) body(l + 1, S2, S0, S1);
    if (l + 2 < L) body(l + 2, S1, S2, S0);
  }

  // epilogue: C/D layout col=lane&15, row=(lane>>4)*4+reg [guide m89]; fused stats
  #pragma unroll
  for (int nt = 0; nt < 2; ++nt) {
    int col = wn + nt * 16 + lr;
    if (col < Ostore) {
      float bv = bias ? bias[col] : 0.f;
      float s1 = 0.f, s2 = 0.f;
      #pragma unroll
      for (int mt = 0; mt < 4; ++mt) {
        #pragma unroll
        for (int rg = 0; rg < 4; ++rg) {
          int row = bm + mt * 16 + lq * 4 + rg;
          float v = acc[mt][nt][rg] + bv;
          Yb[(long)row * Ostore + col] = f2h(v);
          s1 += v; s2 += v * v;
        }
      }
      if (stats) {
        s1 += __shfl_xor(s1, 16); s1 += __shfl_xor(s1, 32);
        s2 += __shfl_xor(s2, 16); s2 += __shfl_xor(s2, 32);
        if (lq == 0) {
          atomicAdd(&stats[col], s1);
          atomicAdd(&stats[Ostore + col], s2);
        }
      }
    }
  }
}

// ---------- stats for enc0 output (O=256), vectorized ----------
__global__ __launch_bounds__(256) void stats2_k(const u16* __restrict__ y, float* __restrict__ st) {
  __shared__ float s1L[256], s2L[256];
  int tid = threadIdx.x;
  int ci = (tid & 63) * 4;
  int r0 = blockIdx.x * 64 + (tid >> 6);
  float a1[4] = {0,0,0,0}, a2[4] = {0,0,0,0};
  for (int it = 0; it < 16; ++it) {
    long i = ((long)r0 + it * 4) * 256 + ci;
    uint2 pv = *(const uint2*)(y + i);
    float v0 = h2f((u16)(pv.x & 0xffff)), v1 = h2f((u16)(pv.x >> 16));
    float v2 = h2f((u16)(pv.y & 0xffff)), v3 = h2f((u16)(pv.y >> 16));
    a1[0] += v0; a1[1] += v1; a1[2] += v2; a1[3] += v3;
    a2[0] += v0*v0; a2[1] += v1*v1; a2[2] += v2*v2; a2[3] += v3*v3;
  }
  s1L[tid] = 0.f; s2L[tid] = 0.f;
  __syncthreads();
  #pragma unroll
  for (int j = 0; j < 4; ++j) { atomicAdd(&s1L[ci + j], a1[j]); atomicAdd(&s2L[ci + j], a2[j]); }
  __syncthreads();
  atomicAdd(&st[tid], s1L[tid]);
  atomicAdd(&st[256 + tid], s2L[tid]);
}

// ---------- vectorized BN+ReLU (+fp16 residual, optional per-channel resid scale) (+SE sums) ----------
__global__ __launch_bounds__(256) void bnrelu2_k(
    const u16* __restrict__ y, const float* __restrict__ st,
    const float* __restrict__ g, const float* __restrict__ be,
    const u16* __restrict__ resid, const float* __restrict__ rscale,
    u16* __restrict__ ob, float* __restrict__ ses, int O)
{
  __shared__ float sL[256];
  int tid = threadIdx.x;
  int tpr = O >> 2;
  int rpi = 256 / tpr;
  int ci = (tid & (tpr - 1)) * 4;
  int row0 = blockIdx.x * (rpi * 16);
  int r0 = row0 + (tid / tpr);
  int b = row0 >> 14;
  float mean[4], sc[4], sh[4], rs[4];
  #pragma unroll
  for (int j = 0; j < 4; ++j) {
    int c = ci + j;
    float m = st[c] * (1.f / 32768.f);
    float var = st[O + c] * (1.f / 32768.f) - m * m;
    mean[j] = m;
    sc[j] = rsqrtf(fmaxf(var, 0.f) + 1e-5f) * g[c];
    sh[j] = be[c];
    rs[j] = rscale ? rscale[b * 256 + c] : 1.f;
  }
  float ss[4] = {0,0,0,0};
  for (int it = 0; it < 16; ++it) {
    long i = ((long)r0 + (long)it * rpi) * O + ci;
    uint2 pv = *(const uint2*)(y + i);
    float v[4];
    v[0] = fmaxf((h2f((u16)(pv.x & 0xffff)) - mean[0]) * sc[0] + sh[0], 0.f);
    v[1] = fmaxf((h2f((u16)(pv.x >> 16))    - mean[1]) * sc[1] + sh[1], 0.f);
    v[2] = fmaxf((h2f((u16)(pv.y & 0xffff)) - mean[2]) * sc[2] + sh[2], 0.f);
    v[3] = fmaxf((h2f((u16)(pv.y >> 16))    - mean[3]) * sc[3] + sh[3], 0.f);
    if (resid) {
      uint2 rv = *(const uint2*)(resid + i);
      v[0] += h2f((u16)(rv.x & 0xffff)) * rs[0]; v[1] += h2f((u16)(rv.x >> 16)) * rs[1];
      v[2] += h2f((u16)(rv.y & 0xffff)) * rs[2]; v[3] += h2f((u16)(rv.y >> 16)) * rs[3];
    }
    uint2 pk;
    pk.x = (unsigned)f2h(v[0]) | ((unsigned)f2h(v[1]) << 16);
    pk.y = (unsigned)f2h(v[2]) | ((unsigned)f2h(v[3]) << 16);
    *(uint2*)(ob + i) = pk;
    #pragma unroll
    for (int j = 0; j < 4; ++j) ss[j] += v[j];
  }
  if (ses) {
    sL[tid] = 0.f;
    __syncthreads();
    #pragma unroll
    for (int j = 0; j < 4; ++j) atomicAdd(&sL[ci + j], ss[j]);
    __syncthreads();
    atomicAdd(&ses[b * O + tid], sL[tid]);
  }
}

// ---------- SE gate ----------
__global__ void se_k(const float* __restrict__ ses, const float* __restrict__ w1,
                     const float* __restrict__ w2, float* __restrict__ sig)
{
  __shared__ float s[256];
  __shared__ float h[32];
  int b = blockIdx.x, t = threadIdx.x;
  s[t] = ses[b * 256 + t] * (1.f / 16384.f);
  __syncthreads();
  if (t < 32) {
    float a = 0.f;
    for (int c = 0; c < 256; ++c) a += w1[t * 256 + c] * s[c];
    h[t] = fmaxf(a, 0.f);
  }
  __syncthreads();
  float a = 0.f;
  #pragma unroll
  for (int r = 0; r < 32; ++r) a += w2[t * 32 + r] * h[r];
  sig[b * 256 + t] = 1.f / (1.f + expf(-a));
}

// ---------- x = out * sig (single use: decoder input materialization) ----------
__global__ __launch_bounds__(256) void scale_k(const u16* __restrict__ t, const float* __restrict__ sig,
                                               u16* __restrict__ xb)
{
  long i = ((long)blockIdx.x * 256 + threadIdx.x) * 4;
  int b = (int)(i >> 22);
  int c = (int)(i & 255);
  uint2 pv = *(const uint2*)(t + i);
  const float* sgp = sig + b * 256 + c;
  float v0 = h2f((u16)(pv.x & 0xffff)) * sgp[0];
  float v1 = h2f((u16)(pv.x >> 16))    * sgp[1];
  float v2 = h2f((u16)(pv.y & 0xffff)) * sgp[2];
  float v3 = h2f((u16)(pv.y >> 16))    * sgp[3];
  uint2 pk;
  pk.x = (unsigned)f2h(v0) | ((unsigned)f2h(v1) << 16);
  pk.y = (unsigned)f2h(v2) | ((unsigned)f2h(v3) << 16);
  *(uint2*)(xb + i) = pk;
}

// ---------- final head ----------
__global__ __launch_bounds__(256) void cls3_k(const u16* __restrict__ h2, const float* __restrict__ w,
                                              const float* __restrict__ b, float* __restrict__ out)
{
  __shared__ float ws[64];
  int t = threadIdx.x;
  if (t < 64) ws[t] = w[t];
  __syncthreads();
  int r = blockIdx.x * 256 + t;
  const u16* p = h2 + (long)r * 64;
  float a = b[0];
  #pragma unroll
  for (int c = 0; c < 64; ++c) a += ws[c] * h2f(p[c]);
  out[r] = a;
}

extern "C" void kernel_launch(void* const* d_in, const int* in_sizes, int n_in,
                              void* d_out, int out_size, void* d_ws, size_t ws_size,
                              hipStream_t stream)
{
  (void)in_sizes; (void)n_in; (void)out_size; (void)ws_size;
  const float* verts   = (const float*)d_in[0];
  const int*   spirals = (const int*)d_in[1];
  const float* enc0_w  = (const float*)d_in[2];
  const float* enc0_g  = (const float*)d_in[4];
  const float* enc0_be = (const float*)d_in[5];
  const float* enc_w   = (const float*)d_in[6];
  const float* enc_g   = (const float*)d_in[8];
  const float* enc_be  = (const float*)d_in[9];
  const float* se_w1   = (const float*)d_in[10];
  const float* se_w2   = (const float*)d_in[11];
  const float* skip_w  = (const float*)d_in[12];
  const float* skip_b  = (const float*)d_in[13];
  const float* dec_w   = (const float*)d_in[14];
  const float* dec_g   = (const float*)d_in[16];
  const float* dec_be  = (const float*)d_in[17];
  const float* cls1_w  = (const float*)d_in[18];
  const float* cls1_g  = (const float*)d_in[20];
  const float* cls1_be = (const float*)d_in[21];
  const float* cls2_w  = (const float*)d_in[22];
  const float* cls2_g  = (const float*)d_in[24];
  const float* cls2_be = (const float*)d_in[25];
  const float* cls3_w  = (const float*)d_in[26];
  const float* cls3_b  = (const float*)d_in[27];

  // --- workspace (~118 MB) ---
  char* p = (char*)d_ws;
  auto alloc = [&](size_t n) { char* q = p; p += (n + 255) & ~(size_t)255; return q; };
  u16* wpe     = (u16*)alloc((size_t)6 * 256 * 3072 * 2);       // 6 permuted conv weights
  u16* wpe_s   = (u16*)alloc((size_t)3 * 2 * 256 * 3072 * 2);   // enc, per-batch SE-folded
  u16* skip_wb = (u16*)alloc((size_t)3 * 256 * 512 * 2);
  u16* skip_s  = (u16*)alloc((size_t)3 * 2 * 256 * 512 * 2);    // skip, per-batch folded
  u16* cls1_wb = (u16*)alloc((size_t)256 * 256 * 2);            // zero-padded to 256 rows
  u16* wp6     = (u16*)alloc((size_t)256 * 128 * 2);            // zero-padded to 256 rows
  float* stats = (float*)alloc(2048);
  float* sesum = (float*)alloc(2048);                           // contiguous after stats
  float* sig   = (float*)alloc(4 * 2048);                       // sig_i = sig + i*512
  u16* out0 = (u16*)alloc((size_t)M_N * 256 * 2);
  u16* out1 = (u16*)alloc((size_t)M_N * 256 * 2);
  u16* out2 = (u16*)alloc((size_t)M_N * 256 * 2);
  u16* ct   = (u16*)alloc((size_t)M_N * 256 * 2);               // conv temp; aliases out3
  u16* tb   = (u16*)alloc((size_t)M_N * 256 * 2);
  u16* xd   = (u16*)alloc((size_t)M_N * 256 * 2);
  u16* outs[4] = {out0, out1, out2, ct};
  const size_t WENC = (size_t)256 * 3072;      // elems per enc weight copy
  const size_t WSKP = (size_t)256 * 512;

  // prep
  perm2_k<<<768, 256, 0, stream>>>(enc_w, wpe);
  perm2_k<<<768, 256, 0, stream>>>(dec_w, wpe + (size_t)3 * WENC);
  cvt_k<<<1536, 256, 0, stream>>>(skip_w, skip_wb, 3 * 256 * 512);
  hipMemsetAsync(cls1_wb, 0, 256 * 256 * 2, stream);
  cvt_k<<<128, 256, 0, stream>>>(cls1_w, cls1_wb, 128 * 256);
  hipMemsetAsync(wp6, 0, 256 * 128 * 2, stream);
  cvt_k<<<32, 256, 0, stream>>>(cls2_w, wp6, 64 * 128);

  // ---- encoder block 0 ----
  hipMemsetAsync(stats, 0, 4096, stream);
  enc0_k<<<1024, 256, 0, stream>>>(verts, spirals, enc0_w, ct);
  stats2_k<<<512, 256, 0, stream>>>(ct, stats);
  bnrelu2_k<<<512, 256, 0, stream>>>(ct, stats, enc0_g, enc0_be, nullptr, nullptr, out0, sesum, 256);
  se_k<<<2, 256, 0, stream>>>(sesum, se_w1, se_w2, sig);

  // ---- encoder blocks 1..3 (SE scale folded into per-batch weights) ----
  for (int i = 1; i < 4; ++i) {
    wscale_k<<<3072, 256, 0, stream>>>(wpe + (size_t)(i - 1) * WENC, sig + (i - 1) * 512,
                                       wpe_s + (size_t)(i - 1) * 2 * WENC, (int)WENC, 255);
    hipMemsetAsync(stats, 0, 4096, stream);
    gemm3_k<256><<<512, 512, 0, stream>>>(outs[i - 1], nullptr, 256,
                                          spirals + (size_t)i * V_N * 12, 12,
                                          wpe_s + (size_t)(i - 1) * 2 * WENC, (long)WENC,
                                          ct, nullptr, 256, stats);
    bnrelu2_k<<<512, 256, 0, stream>>>(ct, stats, enc_g + (i - 1) * 256, enc_be + (i - 1) * 256,
                                       outs[i - 1], sig + (i - 1) * 512, outs[i], sesum, 256);
    se_k<<<2, 256, 0, stream>>>(sesum, se_w1 + (size_t)i * 32 * 256,
                                se_w2 + (size_t)i * 256 * 32, sig + i * 512);
  }

  // decoder input x = out3 * sig3 (materialized once; out3 aliases ct)
  scale_k<<<8192, 256, 0, stream>>>(ct, sig + 3 * 512, xd);

  // ---- decoder blocks ----
  for (int i = 0; i < 3; ++i) {
    wscale_k<<<512, 256, 0, stream>>>(skip_wb + (size_t)i * WSKP, sig + (2 - i) * 512,
                                      skip_s + (size_t)i * 2 * WSKP, (int)WSKP, 511);
    gemm3_k<256><<<512, 512, 0, stream>>>(xd, outs[2 - i], 256, nullptr, 2,
                                          skip_s + (size_t)i * 2 * WSKP, (long)WSKP,
                                          tb, skip_b + i * 256, 256, nullptr);       // x1 -> tb
    hipMemsetAsync(stats, 0, 4096, stream);
    gemm3_k<256><<<512, 512, 0, stream>>>(tb, nullptr, 256,
                                          spirals + (size_t)(2 - i) * V_N * 12, 12,
                                          wpe + (size_t)(3 + i) * WENC, 0,
                                          outs[2 - i], nullptr, 256, stats);          // conv -> out[2-i]
    bnrelu2_k<<<512, 256, 0, stream>>>(outs[2 - i], stats, dec_g + i * 256, dec_be + i * 256,
                                       tb, nullptr, xd, nullptr, 256);                // x -> xd
  }

  // ---- classifier ----
  hipMemsetAsync(stats, 0, 4096, stream);
  gemm3_k<256><<<512, 512, 0, stream>>>(xd, nullptr, 256, nullptr, 1,
                                        cls1_wb, 0, ct, nullptr, 128, stats);
  bnrelu2_k<<<256, 256, 0, stream>>>(ct, stats, cls1_g, cls1_be, nullptr, nullptr, ct, nullptr, 128);
  hipMemsetAsync(stats, 0, 4096, stream);
  gemm3_k<128><<<512, 512, 0, stream>>>(ct, nullptr, 128, nullptr, 1,
                                        wp6, 0, tb, nullptr, 64, stats);
  bnrelu2_k<<<128, 256, 0, stream>>>(tb, stats, cls2_g, cls2_be, nullptr, nullptr, tb, nullptr, 64);
  cls3_k<<<128, 256, 0, stream>>>(tb, cls3_w, cls3_b, (float*)d_out);
}

// Round 4
// 1317.613 us; speedup vs baseline: 1.1052x; 1.1052x over previous
//
#include <hip/hip_runtime.h>

typedef unsigned short u16;
using f16x8 = __attribute__((ext_vector_type(8))) _Float16;  // 8 fp16 (4 VGPRs)
using f32x4 = __attribute__((ext_vector_type(4))) float;

#define V_N 16384
#define M_N 32768

__device__ __forceinline__ float h2f(u16 u) {
  _Float16 h; __builtin_memcpy(&h, &u, 2); return (float)h;
}
__device__ __forceinline__ u16 f2h(float f) {
  _Float16 h = (_Float16)f; u16 u; __builtin_memcpy(&u, &h, 2); return u;
}

// async global->LDS DMA, 16B per lane; LDS dest = wave-uniform base + lane*16
__device__ __forceinline__ void dma16(const u16* g, u16* l) {
  __builtin_amdgcn_global_load_lds(
      (const __attribute__((address_space(1))) void*)(const void*)g,
      (__attribute__((address_space(3))) void*)(void*)l, 16, 0, 0);
}

// counted vmcnt wait (immediate must be a literal)
template<int N> __device__ __forceinline__ void vwait() {
  if constexpr (N == 8)      asm volatile("s_waitcnt vmcnt(8)" ::: "memory");
  else if constexpr (N == 4) asm volatile("s_waitcnt vmcnt(4)" ::: "memory");
  else                       asm volatile("s_waitcnt vmcnt(0)" ::: "memory");
}

// lgkm-drain barrier; vmcnt (in-flight gathers) crosses freely
__device__ __forceinline__ void wgbar() {
  asm volatile("s_waitcnt lgkmcnt(0)" ::: "memory");
  __builtin_amdgcn_s_barrier();
  __builtin_amdgcn_sched_barrier(0);
}

// ---------- prep kernels ----------
// LDS-transpose weight permute: wp[o][t*256+c] = f2h(w[o][c*12+t])
__global__ __launch_bounds__(256) void perm2_k(const float* __restrict__ w, u16* __restrict__ wp) {
  __shared__ u16 l[3072];
  int o = blockIdx.x & 255, layer = blockIdx.x >> 8;
  int t = threadIdx.x;
  const float* src = w + ((size_t)layer * 256 + o) * 3072;
  u16* dst = wp + ((size_t)layer * 256 + o) * 3072;
  float2 v[6];
  #pragma unroll
  for (int q = 0; q < 6; ++q) v[q] = *(const float2*)(src + t * 12 + q * 2);
  const float* vf = (const float*)v;
  #pragma unroll
  for (int m = 0; m < 12; ++m) l[m * 256 + t] = f2h(vf[m]);   // c = t
  __syncthreads();
  unsigned* d32 = (unsigned*)dst;
  const unsigned* l32 = (const unsigned*)l;
  #pragma unroll
  for (int q = 0; q < 6; ++q) d32[t * 6 + q] = l32[t * 6 + q];
}

// flat f32 -> fp16 convert
__global__ __launch_bounds__(256) void cvt_k(const float* __restrict__ w, u16* __restrict__ wb, int n) {
  int i = blockIdx.x * 256 + threadIdx.x;
  if (i < n) wb[i] = f2h(w[i]);
}

// per-batch SE-scale fold into weights: o[b][i] = w[i] * sig[b][channel]
// sel=255: enc conv (all K scaled). sel=511: skip (only k>=256 scaled).
__global__ __launch_bounds__(256) void wscale_k(const u16* __restrict__ w, const float* __restrict__ sig,
                                                u16* __restrict__ o, int n, int sel) {
  int i = blockIdx.x * 256 + threadIdx.x;
  if (i >= n) return;
  float wv = h2f(w[i]);
  int k = i & sel;
  int c = k & 255;
  #pragma unroll
  for (int b = 0; b < 2; ++b) {
    float s = (sel == 511 && k < 256) ? 1.f : sig[b * 256 + c];
    o[(long)b * n + i] = f2h(wv * s);
  }
}

// ---------- encoder block 0 conv (C_in=3, K=36), f32 in -> fp16 out ----------
__global__ __launch_bounds__(256) void enc0_k(const float* __restrict__ verts, const int* __restrict__ sp,
                                              const float* __restrict__ w0, u16* __restrict__ y) {
  __shared__ float xs[32][36];
  int t = threadIdx.x;
  int r0 = blockIdx.x * 32;
  for (int s = t; s < 32 * 12; s += 256) {
    int row = s / 12, tt = s - row * 12;
    int gr = r0 + row;
    int b = gr >> 14, v = gr & (V_N - 1);
    int j = sp[tt * V_N + v];
    const float* p = verts + ((long)b * V_N + j) * 3;
    xs[row][tt]      = p[0];
    xs[row][12 + tt] = p[1];
    xs[row][24 + tt] = p[2];
  }
  __syncthreads();
  float w[36];
  #pragma unroll
  for (int k = 0; k < 36; ++k) w[k] = w0[t * 36 + k];
  for (int row = 0; row < 32; ++row) {
    float a = 0.f;
    #pragma unroll
    for (int k = 0; k < 36; ++k) a += w[k] * xs[row][k];
    y[(long)(r0 + row) * 256 + t] = f2h(a);
  }
}

// ---------- MFMA GEMM: 64M x 256N tile, 512 thr, full-tap DMA pipeline ----------
// Round-2 shape (2 blocks/CU) + decoupled schedule:
//  - 2 full-tap LDS buffers (2x32KB; 128KB/CU at 2 blocks). 12 stages, 12 barriers.
//  - gathers stay global_load_lds (zero VGPR staging -> no spill, round-3 lesson).
//  - B double-buffered in REGISTERS at half-tap granularity, loaded BEFORE the
//    next DMA issue, so compute consumes only ops OLDER than in-flight gathers:
//    in-order vmcnt never forces a gather drain mid-compute.
//  - counted vwait<BL> + lgkm-only barrier: DMA(l+1) crosses the tap-l barrier
//    with ~a full tap of latency cover.
// Ledger at tap-l wait: outstanding = DMA(l)[2*QNH] + idx[<=1] + loadB(l,h0)[BL];
// vwait(BL) retires exactly DMA(l)+idx. sched_barrier(0) fences pin issue
// groups (B loads must not hoist above the DMA builtins).
template<int CT>
__global__ __launch_bounds__(512, 4) void gemm3_k(
    const u16* __restrict__ P0, const u16* __restrict__ P1, int lda,
    const int* __restrict__ sp, int L,
    const u16* __restrict__ Wt, long wstride,
    u16* __restrict__ Yb, const float* __restrict__ bias, int Ostore,
    float* __restrict__ stats)
{
  constexpr int KC   = CT >> 5;          // k-chunks (32 elems) per tap
  constexpr int KCH  = KC >> 1;          // k-chunks per half-tap
  constexpr int HROW = CT >> 1;          // elems per half-row (= CT bytes)
  constexpr int CHT  = CT >> 4;          // 16B chunks per half-row
  constexpr int RSH  = (CHT == 16) ? 4 : 3;
  constexpr int CMSK = CHT - 1;
  constexpr int RPI  = 64 / CHT;         // rows per DMA instruction
  constexpr int RW   = 8;                // rows per wave (64 rows / 8 waves)
  constexpr int QNH  = (RW * CT) / 1024; // DMA instrs per wave per half (2 or 1)
  constexpr int BL   = KCH * 2;          // B loads per half-tap (8 or 4)
  constexpr int HBUF = 64 * HROW;        // elems per half-buffer
  __shared__ __align__(16) u16 lA[2][2 * HBUF];   // 2 full-tap buffers
  const int tid  = threadIdx.x;
  const int wave = tid >> 6, lane = tid & 63;
  const int wn = wave * 32;              // N-split-8: 32 cols per wave
  const int lr = lane & 15, lq = lane >> 4;
  // XCD-aware bijective swizzle (nwg % 8 == 0 for all call sites)
  const int nwg = gridDim.x;
  const int wg = (blockIdx.x & 7) * (nwg >> 3) + (blockIdx.x >> 3);
  const int bm = wg * 64;
  const int batch = bm >> 14;
  const int vbase = bm & (V_N - 1);
  const int qrow = lane >> RSH;          // row within DMA instr
  const int qchunk = lane & CMSK;        // 16B chunk within row
  const bool gat = (sp != nullptr);
  const long rowb = (long)batch * V_N;   // gather row base (rows)
  const u16* Pd1 = P1 ? P1 : P0;
  const u16* Wb = Wt + (long)batch * wstride;
  const int ldw = L * CT;

  // B fragment pointers (2 col-tiles of 16 per wave)
  const u16* bp[2];
  #pragma unroll
  for (int nt = 0; nt < 2; ++nt) bp[nt] = Wb + (long)(wn + nt * 16 + lr) * ldw + lq * 8;

  auto load_idx = [&](int tap) -> int {
    int v = 0;
    if (gat && tap < L && lane < RW) v = sp[(long)tap * V_N + vbase + wave * RW + lane];
    return v;
  };

  // full-tap gather DMA into buffer bsel (both halves; 2*QNH instrs)
  auto dma_tap = [&](int bsel, const u16* src, int idxreg) {
    #pragma unroll
    for (int h = 0; h < 2; ++h) {
      u16* wb = lA[bsel] + h * HBUF + wave * (RW * HROW);
      #pragma unroll
      for (int q = 0; q < QNH; ++q) {
        int rloc = wave * RW + q * RPI + qrow;
        long grow;
        if (gat) grow = rowb + (long)__shfl(idxreg, q * RPI + qrow, 64);
        else     grow = bm + rloc;
        const u16* gp = src + grow * lda + h * HROW + ((qchunk ^ (rloc & 7)) << 3);
        dma16(gp, wb + q * (RPI * HROW));
      }
    }
  };

  auto loadB = [&](int cb, f16x8 (&tB)[BL]) {
    #pragma unroll
    for (int kp = 0; kp < KCH; ++kp)
      #pragma unroll
      for (int nt = 0; nt < 2; ++nt)
        tB[kp * 2 + nt] = *(const f16x8*)(bp[nt] + (long)(cb + kp) * 32);
  };

  f32x4 acc[4][2];
  #pragma unroll
  for (int i = 0; i < 4; ++i)
    #pragma unroll
    for (int j = 0; j < 2; ++j) acc[i][j] = (f32x4){0.f, 0.f, 0.f, 0.f};

  // pure-register compute: no vmem ops -> never forces gather retirement
  auto compute_half = [&](const u16* bufh, const f16x8 (&tB)[BL]) {
    #pragma unroll
    for (int kp = 0; kp < KCH; ++kp) {
      f16x8 a[4];
      #pragma unroll
      for (int mt = 0; mt < 4; ++mt) {
        int row = mt * 16 + lr;
        a[mt] = *(const f16x8*)(&bufh[row * HROW + (((kp * 4 + lq) ^ (row & 7)) << 3)]);
      }
      #pragma unroll
      for (int mt = 0; mt < 4; ++mt)
        #pragma unroll
        for (int nt = 0; nt < 2; ++nt)
          acc[mt][nt] = __builtin_amdgcn_mfma_f32_16x16x32_f16(a[mt], tB[kp * 2 + nt], acc[mt][nt], 0, 0, 0);
    }
  };

  f16x8 tBA[BL], tBB[BL];

  // ---- prologue: DMA(tap0) then loadB(0,h0) (order matters for the ledger) ----
  {
    int idx0 = load_idx(0);
    dma_tap(0, P0, idx0);
  }
  int idxN = load_idx(1);                // for DMA(tap1)
  __builtin_amdgcn_sched_barrier(0);
  loadB(0, tBA);                         // B(0,h0) -- younger than DMA(0)
  __builtin_amdgcn_sched_barrier(0);

  for (int l = 0; l < L; ++l) {
    const u16* sN = gat ? P0 : Pd1;      // source of tap l+1
    vwait<BL>();                         // retires DMA(l)+idx, keeps DMA(l+1)-to-be
    wgbar();                             // buf[l&1] ready for all waves
    loadB(l * KC + KCH, tBB);            // B(l,h1) -- older than DMA(l+1)
    __builtin_amdgcn_sched_barrier(0);
    if (l + 1 < L) dma_tap((l + 1) & 1, sN, idxN);
    int idxF = (gat && l + 2 < L) ? load_idx(l + 2) : 0;
    __builtin_amdgcn_sched_barrier(0);
    compute_half(lA[l & 1], tBA);        // (l,h0)
    __builtin_amdgcn_sched_barrier(0);
    if (l + 1 < L) loadB((l + 1) * KC, tBA);   // B(l+1,h0) -- after DMA(l+1)!
    __builtin_amdgcn_sched_barrier(0);
    compute_half(lA[l & 1] + HBUF, tBB); // (l,h1)
    idxN = idxF;
  }

  // epilogue: C/D layout col=lane&15, row=(lane>>4)*4+reg [guide m89]; fused stats
  #pragma unroll
  for (int nt = 0; nt < 2; ++nt) {
    int col = wn + nt * 16 + lr;
    if (col < Ostore) {
      float bv = bias ? bias[col] : 0.f;
      float s1 = 0.f, s2 = 0.f;
      #pragma unroll
      for (int mt = 0; mt < 4; ++mt) {
        #pragma unroll
        for (int rg = 0; rg < 4; ++rg) {
          int row = bm + mt * 16 + lq * 4 + rg;
          float v = acc[mt][nt][rg] + bv;
          Yb[(long)row * Ostore + col] = f2h(v);
          s1 += v; s2 += v * v;
        }
      }
      if (stats) {
        s1 += __shfl_xor(s1, 16); s1 += __shfl_xor(s1, 32);
        s2 += __shfl_xor(s2, 16); s2 += __shfl_xor(s2, 32);
        if (lq == 0) {
          atomicAdd(&stats[col], s1);
          atomicAdd(&stats[Ostore + col], s2);
        }
      }
    }
  }
}

// ---------- stats for enc0 output (O=256), vectorized ----------
__global__ __launch_bounds__(256) void stats2_k(const u16* __restrict__ y, float* __restrict__ st) {
  __shared__ float s1L[256], s2L[256];
  int tid = threadIdx.x;
  int ci = (tid & 63) * 4;
  int r0 = blockIdx.x * 64 + (tid >> 6);
  float a1[4] = {0,0,0,0}, a2[4] = {0,0,0,0};
  for (int it = 0; it < 16; ++it) {
    long i = ((long)r0 + it * 4) * 256 + ci;
    uint2 pv = *(const uint2*)(y + i);
    float v0 = h2f((u16)(pv.x & 0xffff)), v1 = h2f((u16)(pv.x >> 16));
    float v2 = h2f((u16)(pv.y & 0xffff)), v3 = h2f((u16)(pv.y >> 16));
    a1[0] += v0; a1[1] += v1; a1[2] += v2; a1[3] += v3;
    a2[0] += v0*v0; a2[1] += v1*v1; a2[2] += v2*v2; a2[3] += v3*v3;
  }
  s1L[tid] = 0.f; s2L[tid] = 0.f;
  __syncthreads();
  #pragma unroll
  for (int j = 0; j < 4; ++j) { atomicAdd(&s1L[ci + j], a1[j]); atomicAdd(&s2L[ci + j], a2[j]); }
  __syncthreads();
  atomicAdd(&st[tid], s1L[tid]);
  atomicAdd(&st[256 + tid], s2L[tid]);
}

// ---------- vectorized BN+ReLU (+fp16 residual, optional per-channel resid scale) (+SE sums) ----------
__global__ __launch_bounds__(256) void bnrelu2_k(
    const u16* __restrict__ y, const float* __restrict__ st,
    const float* __restrict__ g, const float* __restrict__ be,
    const u16* __restrict__ resid, const float* __restrict__ rscale,
    u16* __restrict__ ob, float* __restrict__ ses, int O)
{
  __shared__ float sL[256];
  int tid = threadIdx.x;
  int tpr = O >> 2;
  int rpi = 256 / tpr;
  int ci = (tid & (tpr - 1)) * 4;
  int row0 = blockIdx.x * (rpi * 16);
  int r0 = row0 + (tid / tpr);
  int b = row0 >> 14;
  float mean[4], sc[4], sh[4], rs[4];
  #pragma unroll
  for (int j = 0; j < 4; ++j) {
    int c = ci + j;
    float m = st[c] * (1.f / 32768.f);
    float var = st[O + c] * (1.f / 32768.f) - m * m;
    mean[j] = m;
    sc[j] = rsqrtf(fmaxf(var, 0.f) + 1e-5f) * g[c];
    sh[j] = be[c];
    rs[j] = rscale ? rscale[b * 256 + c] : 1.f;
  }
  float ss[4] = {0,0,0,0};
  for (int it = 0; it < 16; ++it) {
    long i = ((long)r0 + (long)it * rpi) * O + ci;
    uint2 pv = *(const uint2*)(y + i);
    float v[4];
    v[0] = fmaxf((h2f((u16)(pv.x & 0xffff)) - mean[0]) * sc[0] + sh[0], 0.f);
    v[1] = fmaxf((h2f((u16)(pv.x >> 16))    - mean[1]) * sc[1] + sh[1], 0.f);
    v[2] = fmaxf((h2f((u16)(pv.y & 0xffff)) - mean[2]) * sc[2] + sh[2], 0.f);
    v[3] = fmaxf((h2f((u16)(pv.y >> 16))    - mean[3]) * sc[3] + sh[3], 0.f);
    if (resid) {
      uint2 rv = *(const uint2*)(resid + i);
      v[0] += h2f((u16)(rv.x & 0xffff)) * rs[0]; v[1] += h2f((u16)(rv.x >> 16)) * rs[1];
      v[2] += h2f((u16)(rv.y & 0xffff)) * rs[2]; v[3] += h2f((u16)(rv.y >> 16)) * rs[3];
    }
    uint2 pk;
    pk.x = (unsigned)f2h(v[0]) | ((unsigned)f2h(v[1]) << 16);
    pk.y = (unsigned)f2h(v[2]) | ((unsigned)f2h(v[3]) << 16);
    *(uint2*)(ob + i) = pk;
    #pragma unroll
    for (int j = 0; j < 4; ++j) ss[j] += v[j];
  }
  if (ses) {
    sL[tid] = 0.f;
    __syncthreads();
    #pragma unroll
    for (int j = 0; j < 4; ++j) atomicAdd(&sL[ci + j], ss[j]);
    __syncthreads();
    atomicAdd(&ses[b * O + tid], sL[tid]);
  }
}

// ---------- SE gate ----------
__global__ void se_k(const float* __restrict__ ses, const float* __restrict__ w1,
                     const float* __restrict__ w2, float* __restrict__ sig)
{
  __shared__ float s[256];
  __shared__ float h[32];
  int b = blockIdx.x, t = threadIdx.x;
  s[t] = ses[b * 256 + t] * (1.f / 16384.f);
  __syncthreads();
  if (t < 32) {
    float a = 0.f;
    for (int c = 0; c < 256; ++c) a += w1[t * 256 + c] * s[c];
    h[t] = fmaxf(a, 0.f);
  }
  __syncthreads();
  float a = 0.f;
  #pragma unroll
  for (int r = 0; r < 32; ++r) a += w2[t * 32 + r] * h[r];
  sig[b * 256 + t] = 1.f / (1.f + expf(-a));
}

// ---------- x = out * sig (single use: decoder input materialization) ----------
__global__ __launch_bounds__(256) void scale_k(const u16* __restrict__ t, const float* __restrict__ sig,
                                               u16* __restrict__ xb)
{
  long i = ((long)blockIdx.x * 256 + threadIdx.x) * 4;
  int b = (int)(i >> 22);
  int c = (int)(i & 255);
  uint2 pv = *(const uint2*)(t + i);
  const float* sgp = sig + b * 256 + c;
  float v0 = h2f((u16)(pv.x & 0xffff)) * sgp[0];
  float v1 = h2f((u16)(pv.x >> 16))    * sgp[1];
  float v2 = h2f((u16)(pv.y & 0xffff)) * sgp[2];
  float v3 = h2f((u16)(pv.y >> 16))    * sgp[3];
  uint2 pk;
  pk.x = (unsigned)f2h(v0) | ((unsigned)f2h(v1) << 16);
  pk.y = (unsigned)f2h(v2) | ((unsigned)f2h(v3) << 16);
  *(uint2*)(xb + i) = pk;
}

// ---------- final head ----------
__global__ __launch_bounds__(256) void cls3_k(const u16* __restrict__ h2, const float* __restrict__ w,
                                              const float* __restrict__ b, float* __restrict__ out)
{
  __shared__ float ws[64];
  int t = threadIdx.x;
  if (t < 64) ws[t] = w[t];
  __syncthreads();
  int r = blockIdx.x * 256 + t;
  const u16* p = h2 + (long)r * 64;
  float a = b[0];
  #pragma unroll
  for (int c = 0; c < 64; ++c) a += ws[c] * h2f(p[c]);
  out[r] = a;
}

extern "C" void kernel_launch(void* const* d_in, const int* in_sizes, int n_in,
                              void* d_out, int out_size, void* d_ws, size_t ws_size,
                              hipStream_t stream)
{
  (void)in_sizes; (void)n_in; (void)out_size; (void)ws_size;
  const float* verts   = (const float*)d_in[0];
  const int*   spirals = (const int*)d_in[1];
  const float* enc0_w  = (const float*)d_in[2];
  const float* enc0_g  = (const float*)d_in[4];
  const float* enc0_be = (const float*)d_in[5];
  const float* enc_w   = (const float*)d_in[6];
  const float* enc_g   = (const float*)d_in[8];
  const float* enc_be  = (const float*)d_in[9];
  const float* se_w1   = (const float*)d_in[10];
  const float* se_w2   = (const float*)d_in[11];
  const float* skip_w  = (const float*)d_in[12];
  const float* skip_b  = (const float*)d_in[13];
  const float* dec_w   = (const float*)d_in[14];
  const float* dec_g   = (const float*)d_in[16];
  const float* dec_be  = (const float*)d_in[17];
  const float* cls1_w  = (const float*)d_in[18];
  const float* cls1_g  = (const float*)d_in[20];
  const float* cls1_be = (const float*)d_in[21];
  const float* cls2_w  = (const float*)d_in[22];
  const float* cls2_g  = (const float*)d_in[24];
  const float* cls2_be = (const float*)d_in[25];
  const float* cls3_w  = (const float*)d_in[26];
  const float* cls3_b  = (const float*)d_in[27];

  // --- workspace (~118 MB) ---
  char* p = (char*)d_ws;
  auto alloc = [&](size_t n) { char* q = p; p += (n + 255) & ~(size_t)255; return q; };
  u16* wpe     = (u16*)alloc((size_t)6 * 256 * 3072 * 2);       // 6 permuted conv weights
  u16* wpe_s   = (u16*)alloc((size_t)3 * 2 * 256 * 3072 * 2);   // enc, per-batch SE-folded
  u16* skip_wb = (u16*)alloc((size_t)3 * 256 * 512 * 2);
  u16* skip_s  = (u16*)alloc((size_t)3 * 2 * 256 * 512 * 2);    // skip, per-batch folded
  u16* cls1_wb = (u16*)alloc((size_t)256 * 256 * 2);            // zero-padded to 256 rows
  u16* wp6     = (u16*)alloc((size_t)256 * 128 * 2);            // zero-padded to 256 rows
  float* stats = (float*)alloc(2048);
  float* sesum = (float*)alloc(2048);                           // contiguous after stats
  float* sig   = (float*)alloc(4 * 2048);                       // sig_i = sig + i*512
  u16* out0 = (u16*)alloc((size_t)M_N * 256 * 2);
  u16* out1 = (u16*)alloc((size_t)M_N * 256 * 2);
  u16* out2 = (u16*)alloc((size_t)M_N * 256 * 2);
  u16* ct   = (u16*)alloc((size_t)M_N * 256 * 2);               // conv temp; aliases out3
  u16* tb   = (u16*)alloc((size_t)M_N * 256 * 2);
  u16* xd   = (u16*)alloc((size_t)M_N * 256 * 2);
  u16* outs[4] = {out0, out1, out2, ct};
  const size_t WENC = (size_t)256 * 3072;      // elems per enc weight copy
  const size_t WSKP = (size_t)256 * 512;

  // prep
  perm2_k<<<768, 256, 0, stream>>>(enc_w, wpe);
  perm2_k<<<768, 256, 0, stream>>>(dec_w, wpe + (size_t)3 * WENC);
  cvt_k<<<1536, 256, 0, stream>>>(skip_w, skip_wb, 3 * 256 * 512);
  hipMemsetAsync(cls1_wb, 0, 256 * 256 * 2, stream);
  cvt_k<<<128, 256, 0, stream>>>(cls1_w, cls1_wb, 128 * 256);
  hipMemsetAsync(wp6, 0, 256 * 128 * 2, stream);
  cvt_k<<<32, 256, 0, stream>>>(cls2_w, wp6, 64 * 128);

  // ---- encoder block 0 ----
  hipMemsetAsync(stats, 0, 4096, stream);
  enc0_k<<<1024, 256, 0, stream>>>(verts, spirals, enc0_w, ct);
  stats2_k<<<512, 256, 0, stream>>>(ct, stats);
  bnrelu2_k<<<512, 256, 0, stream>>>(ct, stats, enc0_g, enc0_be, nullptr, nullptr, out0, sesum, 256);
  se_k<<<2, 256, 0, stream>>>(sesum, se_w1, se_w2, sig);

  // ---- encoder blocks 1..3 (SE scale folded into per-batch weights) ----
  for (int i = 1; i < 4; ++i) {
    wscale_k<<<3072, 256, 0, stream>>>(wpe + (size_t)(i - 1) * WENC, sig + (i - 1) * 512,
                                       wpe_s + (size_t)(i - 1) * 2 * WENC, (int)WENC, 255);
    hipMemsetAsync(stats, 0, 4096, stream);
    gemm3_k<256><<<512, 512, 0, stream>>>(outs[i - 1], nullptr, 256,
                                          spirals + (size_t)i * V_N * 12, 12,
                                          wpe_s + (size_t)(i - 1) * 2 * WENC, (long)WENC,
                                          ct, nullptr, 256, stats);
    bnrelu2_k<<<512, 256, 0, stream>>>(ct, stats, enc_g + (i - 1) * 256, enc_be + (i - 1) * 256,
                                       outs[i - 1], sig + (i - 1) * 512, outs[i], sesum, 256);
    se_k<<<2, 256, 0, stream>>>(sesum, se_w1 + (size_t)i * 32 * 256,
                                se_w2 + (size_t)i * 256 * 32, sig + i * 512);
  }

  // decoder input x = out3 * sig3 (materialized once; out3 aliases ct)
  scale_k<<<8192, 256, 0, stream>>>(ct, sig + 3 * 512, xd);

  // ---- decoder blocks ----
  for (int i = 0; i < 3; ++i) {
    wscale_k<<<512, 256, 0, stream>>>(skip_wb + (size_t)i * WSKP, sig + (2 - i) * 512,
                                      skip_s + (size_t)i * 2 * WSKP, (int)WSKP, 511);
    gemm3_k<256><<<512, 512, 0, stream>>>(xd, outs[2 - i], 256, nullptr, 2,
                                          skip_s + (size_t)i * 2 * WSKP, (long)WSKP,
                                          tb, skip_b + i * 256, 256, nullptr);       // x1 -> tb
    hipMemsetAsync(stats, 0, 4096, stream);
    gemm3_k<256><<<512, 512, 0, stream>>>(tb, nullptr, 256,
                                          spirals + (size_t)(2 - i) * V_N * 12, 12,
                                          wpe + (size_t)(3 + i) * WENC, 0,
                                          outs[2 - i], nullptr, 256, stats);          // conv -> out[2-i]
    bnrelu2_k<<<512, 256, 0, stream>>>(outs[2 - i], stats, dec_g + i * 256, dec_be + i * 256,
                                       tb, nullptr, xd, nullptr, 256);                // x -> xd
  }

  // ---- classifier ----
  hipMemsetAsync(stats, 0, 4096, stream);
  gemm3_k<256><<<512, 512, 0, stream>>>(xd, nullptr, 256, nullptr, 1,
                                        cls1_wb, 0, ct, nullptr, 128, stats);
  bnrelu2_k<<<256, 256, 0, stream>>>(ct, stats, cls1_g, cls1_be, nullptr, nullptr, ct, nullptr, 128);
  hipMemsetAsync(stats, 0, 4096, stream);
  gemm3_k<128><<<512, 512, 0, stream>>>(ct, nullptr, 128, nullptr, 1,
                                        wp6, 0, tb, nullptr, 64, stats);
  bnrelu2_k<<<128, 256, 0, stream>>>(tb, stats, cls2_g, cls2_be, nullptr, nullptr, tb, nullptr, 64);
  cls3_k<<<128, 256, 0, stream>>>(tb, cls3_w, cls3_b, (float*)d_out);
}

// Round 5
// 1124.227 us; speedup vs baseline: 1.2953x; 1.1720x over previous
//
#include <hip/hip_runtime.h>

typedef unsigned short u16;
using f16x8 = __attribute__((ext_vector_type(8))) _Float16;  // 8 fp16 (4 VGPRs)
using f32x4 = __attribute__((ext_vector_type(4))) float;

#define V_N 16384
#define M_N 32768

__device__ __forceinline__ float h2f(u16 u) {
  _Float16 h; __builtin_memcpy(&h, &u, 2); return (float)h;
}
__device__ __forceinline__ u16 f2h(float f) {
  _Float16 h = (_Float16)f; u16 u; __builtin_memcpy(&u, &h, 2); return u;
}

// async global->LDS DMA, 16B per lane; LDS dest = wave-uniform base + lane*16
__device__ __forceinline__ void dma16(const u16* g, u16* l) {
  __builtin_amdgcn_global_load_lds(
      (const __attribute__((address_space(1))) void*)(const void*)g,
      (__attribute__((address_space(3))) void*)(void*)l, 16, 0, 0);
}

// ---------- prep kernels ----------
// LDS-transpose weight permute: wp[o][t*256+c] = f2h(w[o][c*12+t])
__global__ __launch_bounds__(256) void perm2_k(const float* __restrict__ w, u16* __restrict__ wp) {
  __shared__ u16 l[3072];
  int o = blockIdx.x & 255, layer = blockIdx.x >> 8;
  int t = threadIdx.x;
  const float* src = w + ((size_t)layer * 256 + o) * 3072;
  u16* dst = wp + ((size_t)layer * 256 + o) * 3072;
  float2 v[6];
  #pragma unroll
  for (int q = 0; q < 6; ++q) v[q] = *(const float2*)(src + t * 12 + q * 2);
  const float* vf = (const float*)v;
  #pragma unroll
  for (int m = 0; m < 12; ++m) l[m * 256 + t] = f2h(vf[m]);   // c = t
  __syncthreads();
  unsigned* d32 = (unsigned*)dst;
  const unsigned* l32 = (const unsigned*)l;
  #pragma unroll
  for (int q = 0; q < 6; ++q) d32[t * 6 + q] = l32[t * 6 + q];
}

// flat f32 -> fp16 convert
__global__ __launch_bounds__(256) void cvt_k(const float* __restrict__ w, u16* __restrict__ wb, int n) {
  int i = blockIdx.x * 256 + threadIdx.x;
  if (i < n) wb[i] = f2h(w[i]);
}

// per-batch SE-scale fold into weights: o[b][i] = w[i] * s
// sel=255: enc conv (all K scaled by sig).
// sel=511: skip (k>=256 scaled by sig; k<256 scaled by sigx if non-null, else 1).
__global__ __launch_bounds__(256) void wscale_k(const u16* __restrict__ w, const float* __restrict__ sig,
                                                const float* __restrict__ sigx,
                                                u16* __restrict__ o, int n, int sel) {
  int i = blockIdx.x * 256 + threadIdx.x;
  if (i >= n) return;
  float wv = h2f(w[i]);
  int k = i & sel;
  int c = k & 255;
  #pragma unroll
  for (int b = 0; b < 2; ++b) {
    float s;
    if (sel == 511 && k < 256) s = sigx ? sigx[b * 256 + c] : 1.f;
    else                       s = sig[b * 256 + c];
    o[(long)b * n + i] = f2h(wv * s);
  }
}

// ---------- encoder block 0 conv (C_in=3, K=36), f32 in -> fp16 out ----------
__global__ __launch_bounds__(256) void enc0_k(const float* __restrict__ verts, const int* __restrict__ sp,
                                              const float* __restrict__ w0, u16* __restrict__ y) {
  __shared__ float xs[32][36];
  int t = threadIdx.x;
  int r0 = blockIdx.x * 32;
  for (int s = t; s < 32 * 12; s += 256) {
    int row = s / 12, tt = s - row * 12;
    int gr = r0 + row;
    int b = gr >> 14, v = gr & (V_N - 1);
    int j = sp[tt * V_N + v];
    const float* p = verts + ((long)b * V_N + j) * 3;
    xs[row][tt]      = p[0];
    xs[row][12 + tt] = p[1];
    xs[row][24 + tt] = p[2];
  }
  __syncthreads();
  float w[36];
  #pragma unroll
  for (int k = 0; k < 36; ++k) w[k] = w0[t * 36 + k];
  for (int row = 0; row < 32; ++row) {
    float a = 0.f;
    #pragma unroll
    for (int k = 0; k < 36; ++k) a += w[k] * xs[row][k];
    y[(long)(r0 + row) * 256 + t] = f2h(a);
  }
}

// ---------- MFMA GEMM: 64M x 256N tile, 512 thr, K-PHASE-SPLIT gather ----------
// Gather-BW fix (R0-R4 lesson: per-stage time ∝ gather volume; schedule-depth
// and occupancy changes were all neutral -> gather path is throughput-bound,
// ~1.7 TB/s for random 512B rows from an 8MB/XCD working set that thrashes L2).
// Phase-major K loop: split each row into PH column-slices of 128B and sweep
// ALL taps within a slice. Per phase per XCD: gather set = 16384 x 128B = 2MB,
// B-slice = 384KB -> BOTH L2-resident -> each line hit ~12x in L2.
// Structure: R2's proven drain-barrier double-buffer (no asm waitcnt); 2x8KB
// LDS buffers; B reg-double-buffered (loaded 1 stage ahead); 2 blocks/CU.
// Stage s (of PH*L): tap l = s%L, phase ph = s/L; B chunk base = l*KC + ph*KCP.
template<int CT>
__global__ __launch_bounds__(512, 4) void gemm3_k(
    const u16* __restrict__ P0, const u16* __restrict__ P1, int lda,
    const int* __restrict__ sp, int L,
    const u16* __restrict__ Wt, long wstride,
    u16* __restrict__ Yb, const float* __restrict__ bias, int Ostore,
    float* __restrict__ stats)
{
  constexpr int KC   = CT >> 5;            // k-chunks (32 elems) per tap (8 or 4)
  constexpr int PH   = (CT == 256) ? 4 : 2;// phases -> 64-elem slice always
  constexpr int KCP  = KC / PH;            // k-chunks per stage = 2
  constexpr int PROW = 64;                 // elems per row per stage (128B)
  __shared__ __align__(16) u16 lA[2][64 * PROW];   // 2 x 8KB stage buffers
  const int tid  = threadIdx.x;
  const int wave = tid >> 6, lane = tid & 63;
  const int wn = wave * 32;                // N-split-8: 32 cols per wave
  const int lr = lane & 15, lq = lane >> 4;
  // XCD-aware bijective swizzle (nwg % 8 == 0 for all call sites)
  const int nwg = gridDim.x;
  const int wg = (blockIdx.x & 7) * (nwg >> 3) + (blockIdx.x >> 3);
  const int bm = wg * 64;
  const int batch = bm >> 14;
  const int vbase = bm & (V_N - 1);
  const int qrow = lane >> 3;              // row within DMA instr (8 rows/instr)
  const int qchunk = lane & 7;             // 16B chunk within 128B slice
  const bool gat = (sp != nullptr);
  const long rowb = (long)batch * V_N;     // gather row base (rows)
  const u16* Pd1 = P1 ? P1 : P0;
  const u16* Wb = Wt + (long)batch * wstride;
  const int ldw = L * CT;
  const int NS = PH * L;                   // total stages

  // B fragment pointers (2 col-tiles of 16 per wave)
  const u16* bp[2];
  #pragma unroll
  for (int nt = 0; nt < 2; ++nt) bp[nt] = Wb + (long)(wn + nt * 16 + lr) * ldw + lq * 8;

  auto load_idx = [&](int tap) -> int {
    int v = 0;
    if (gat && lane < 8) v = sp[(long)tap * V_N + vbase + wave * 8 + lane];
    return v;
  };

  // stage DMA: 64 rows x 128B slice; wave w covers rows [w*8, w*8+8), 1 instr
  auto dma_st = [&](int sb, const u16* src, int idxreg, int ph) {
    u16* wb = lA[sb] + wave * (8 * PROW);
    int rloc = wave * 8 + qrow;
    long grow;
    if (gat) grow = rowb + (long)__shfl(idxreg, qrow, 64);
    else     grow = bm + rloc;
    const u16* gp = src + grow * lda + ph * PROW + ((qchunk ^ (rloc & 7)) << 3);
    dma16(gp, wb);
  };

  auto loadB = [&](int cb, f16x8 (&tB)[KCP * 2]) {
    #pragma unroll
    for (int kp = 0; kp < KCP; ++kp)
      #pragma unroll
      for (int nt = 0; nt < 2; ++nt)
        tB[kp * 2 + nt] = *(const f16x8*)(bp[nt] + (long)(cb + kp) * 32);
  };

  f32x4 acc[4][2];
  #pragma unroll
  for (int i = 0; i < 4; ++i)
    #pragma unroll
    for (int j = 0; j < 2; ++j) acc[i][j] = (f32x4){0.f, 0.f, 0.f, 0.f};

  auto compute_st = [&](int sb, const f16x8 (&tB)[KCP * 2]) {
    #pragma unroll
    for (int kp = 0; kp < KCP; ++kp) {
      f16x8 a[4];
      #pragma unroll
      for (int mt = 0; mt < 4; ++mt) {
        int row = mt * 16 + lr;
        a[mt] = *(const f16x8*)(&lA[sb][row * PROW + (((kp * 4 + lq) ^ (row & 7)) << 3)]);
      }
      #pragma unroll
      for (int mt = 0; mt < 4; ++mt)
        #pragma unroll
        for (int nt = 0; nt < 2; ++nt)
          acc[mt][nt] = __builtin_amdgcn_mfma_f32_16x16x32_f16(a[mt], tB[kp * 2 + nt], acc[mt][nt], 0, 0, 0);
    }
  };

  f16x8 tBc[KCP * 2], tBn[KCP * 2];

  // ---- prologue: stage 0 = (tap0, ph0) ----
  int idxC = load_idx(0);
  dma_st(0, P0, idxC, 0);
  loadB(0, tBc);
  int idxN = (gat && L > 1) ? load_idx(1) : idxC;   // tap of stage 1

  int l = 0, ph = 0;
  for (int s = 0; s < NS; ++s) {
    int ln  = (l + 1 == L) ? 0 : l + 1;             // tap of stage s+1
    int phn = (l + 1 == L) ? ph + 1 : ph;           // phase of stage s+1
    __syncthreads();                                 // drains DMA(s)
    if (s + 1 < NS) {
      const u16* srcN = (!gat && ln > 0) ? Pd1 : P0;
      dma_st((s + 1) & 1, srcN, idxN, phn);
      loadB(ln * KC + phn * KCP, tBn);
    }
    int idxF = 0;
    if (gat && s + 2 < NS) {
      int l2 = (ln + 1 == L) ? 0 : ln + 1;          // tap of stage s+2
      idxF = load_idx(l2);
    }
    compute_st(s & 1, tBc);
    #pragma unroll
    for (int i = 0; i < KCP * 2; ++i) tBc[i] = tBn[i];
    idxN = idxF;
    l = ln; ph = phn;
  }

  // epilogue: C/D layout col=lane&15, row=(lane>>4)*4+reg [guide m89]; fused stats
  #pragma unroll
  for (int nt = 0; nt < 2; ++nt) {
    int col = wn + nt * 16 + lr;
    if (col < Ostore) {
      float bv = bias ? bias[col] : 0.f;
      float s1 = 0.f, s2 = 0.f;
      #pragma unroll
      for (int mt = 0; mt < 4; ++mt) {
        #pragma unroll
        for (int rg = 0; rg < 4; ++rg) {
          int row = bm + mt * 16 + lq * 4 + rg;
          float v = acc[mt][nt][rg] + bv;
          Yb[(long)row * Ostore + col] = f2h(v);
          s1 += v; s2 += v * v;
        }
      }
      if (stats) {
        s1 += __shfl_xor(s1, 16); s1 += __shfl_xor(s1, 32);
        s2 += __shfl_xor(s2, 16); s2 += __shfl_xor(s2, 32);
        if (lq == 0) {
          atomicAdd(&stats[col], s1);
          atomicAdd(&stats[Ostore + col], s2);
        }
      }
    }
  }
}

// ---------- stats for enc0 output (O=256), vectorized ----------
__global__ __launch_bounds__(256) void stats2_k(const u16* __restrict__ y, float* __restrict__ st) {
  __shared__ float s1L[256], s2L[256];
  int tid = threadIdx.x;
  int ci = (tid & 63) * 4;
  int r0 = blockIdx.x * 64 + (tid >> 6);
  float a1[4] = {0,0,0,0}, a2[4] = {0,0,0,0};
  for (int it = 0; it < 16; ++it) {
    long i = ((long)r0 + it * 4) * 256 + ci;
    uint2 pv = *(const uint2*)(y + i);
    float v0 = h2f((u16)(pv.x & 0xffff)), v1 = h2f((u16)(pv.x >> 16));
    float v2 = h2f((u16)(pv.y & 0xffff)), v3 = h2f((u16)(pv.y >> 16));
    a1[0] += v0; a1[1] += v1; a1[2] += v2; a1[3] += v3;
    a2[0] += v0*v0; a2[1] += v1*v1; a2[2] += v2*v2; a2[3] += v3*v3;
  }
  s1L[tid] = 0.f; s2L[tid] = 0.f;
  __syncthreads();
  #pragma unroll
  for (int j = 0; j < 4; ++j) { atomicAdd(&s1L[ci + j], a1[j]); atomicAdd(&s2L[ci + j], a2[j]); }
  __syncthreads();
  atomicAdd(&st[tid], s1L[tid]);
  atomicAdd(&st[256 + tid], s2L[tid]);
}

// ---------- vectorized BN+ReLU (+fp16 residual, optional per-channel resid scale) (+SE sums) ----------
__global__ __launch_bounds__(256) void bnrelu2_k(
    const u16* __restrict__ y, const float* __restrict__ st,
    const float* __restrict__ g, const float* __restrict__ be,
    const u16* __restrict__ resid, const float* __restrict__ rscale,
    u16* __restrict__ ob, float* __restrict__ ses, int O)
{
  __shared__ float sL[256];
  int tid = threadIdx.x;
  int tpr = O >> 2;
  int rpi = 256 / tpr;
  int ci = (tid & (tpr - 1)) * 4;
  int row0 = blockIdx.x * (rpi * 16);
  int r0 = row0 + (tid / tpr);
  int b = row0 >> 14;
  float mean[4], sc[4], sh[4], rs[4];
  #pragma unroll
  for (int j = 0; j < 4; ++j) {
    int c = ci + j;
    float m = st[c] * (1.f / 32768.f);
    float var = st[O + c] * (1.f / 32768.f) - m * m;
    mean[j] = m;
    sc[j] = rsqrtf(fmaxf(var, 0.f) + 1e-5f) * g[c];
    sh[j] = be[c];
    rs[j] = rscale ? rscale[b * 256 + c] : 1.f;
  }
  float ss[4] = {0,0,0,0};
  for (int it = 0; it < 16; ++it) {
    long i = ((long)r0 + (long)it * rpi) * O + ci;
    uint2 pv = *(const uint2*)(y + i);
    float v[4];
    v[0] = fmaxf((h2f((u16)(pv.x & 0xffff)) - mean[0]) * sc[0] + sh[0], 0.f);
    v[1] = fmaxf((h2f((u16)(pv.x >> 16))    - mean[1]) * sc[1] + sh[1], 0.f);
    v[2] = fmaxf((h2f((u16)(pv.y & 0xffff)) - mean[2]) * sc[2] + sh[2], 0.f);
    v[3] = fmaxf((h2f((u16)(pv.y >> 16))    - mean[3]) * sc[3] + sh[3], 0.f);
    if (resid) {
      uint2 rv = *(const uint2*)(resid + i);
      v[0] += h2f((u16)(rv.x & 0xffff)) * rs[0]; v[1] += h2f((u16)(rv.x >> 16)) * rs[1];
      v[2] += h2f((u16)(rv.y & 0xffff)) * rs[2]; v[3] += h2f((u16)(rv.y >> 16)) * rs[3];
    }
    uint2 pk;
    pk.x = (unsigned)f2h(v[0]) | ((unsigned)f2h(v[1]) << 16);
    pk.y = (unsigned)f2h(v[2]) | ((unsigned)f2h(v[3]) << 16);
    *(uint2*)(ob + i) = pk;
    #pragma unroll
    for (int j = 0; j < 4; ++j) ss[j] += v[j];
  }
  if (ses) {
    sL[tid] = 0.f;
    __syncthreads();
    #pragma unroll
    for (int j = 0; j < 4; ++j) atomicAdd(&sL[ci + j], ss[j]);
    __syncthreads();
    atomicAdd(&ses[b * O + tid], sL[tid]);
  }
}

// ---------- SE gate ----------
__global__ void se_k(const float* __restrict__ ses, const float* __restrict__ w1,
                     const float* __restrict__ w2, float* __restrict__ sig)
{
  __shared__ float s[256];
  __shared__ float h[32];
  int b = blockIdx.x, t = threadIdx.x;
  s[t] = ses[b * 256 + t] * (1.f / 16384.f);
  __syncthreads();
  if (t < 32) {
    float a = 0.f;
    for (int c = 0; c < 256; ++c) a += w1[t * 256 + c] * s[c];
    h[t] = fmaxf(a, 0.f);
  }
  __syncthreads();
  float a = 0.f;
  #pragma unroll
  for (int r = 0; r < 32; ++r) a += w2[t * 32 + r] * h[r];
  sig[b * 256 + t] = 1.f / (1.f + expf(-a));
}

// ---------- final head ----------
__global__ __launch_bounds__(256) void cls3_k(const u16* __restrict__ h2, const float* __restrict__ w,
                                              const float* __restrict__ b, float* __restrict__ out)
{
  __shared__ float ws[64];
  int t = threadIdx.x;
  if (t < 64) ws[t] = w[t];
  __syncthreads();
  int r = blockIdx.x * 256 + t;
  const u16* p = h2 + (long)r * 64;
  float a = b[0];
  #pragma unroll
  for (int c = 0; c < 64; ++c) a += ws[c] * h2f(p[c]);
  out[r] = a;
}

extern "C" void kernel_launch(void* const* d_in, const int* in_sizes, int n_in,
                              void* d_out, int out_size, void* d_ws, size_t ws_size,
                              hipStream_t stream)
{
  (void)in_sizes; (void)n_in; (void)out_size; (void)ws_size;
  const float* verts   = (const float*)d_in[0];
  const int*   spirals = (const int*)d_in[1];
  const float* enc0_w  = (const float*)d_in[2];
  const float* enc0_g  = (const float*)d_in[4];
  const float* enc0_be = (const float*)d_in[5];
  const float* enc_w   = (const float*)d_in[6];
  const float* enc_g   = (const float*)d_in[8];
  const float* enc_be  = (const float*)d_in[9];
  const float* se_w1   = (const float*)d_in[10];
  const float* se_w2   = (const float*)d_in[11];
  const float* skip_w  = (const float*)d_in[12];
  const float* skip_b  = (const float*)d_in[13];
  const float* dec_w   = (const float*)d_in[14];
  const float* dec_g   = (const float*)d_in[16];
  const float* dec_be  = (const float*)d_in[17];
  const float* cls1_w  = (const float*)d_in[18];
  const float* cls1_g  = (const float*)d_in[20];
  const float* cls1_be = (const float*)d_in[21];
  const float* cls2_w  = (const float*)d_in[22];
  const float* cls2_g  = (const float*)d_in[24];
  const float* cls2_be = (const float*)d_in[25];
  const float* cls3_w  = (const float*)d_in[26];
  const float* cls3_b  = (const float*)d_in[27];

  // --- workspace (~118 MB) ---
  char* p = (char*)d_ws;
  auto alloc = [&](size_t n) { char* q = p; p += (n + 255) & ~(size_t)255; return q; };
  u16* wpe     = (u16*)alloc((size_t)6 * 256 * 3072 * 2);       // 6 permuted conv weights
  u16* wpe_s   = (u16*)alloc((size_t)3 * 2 * 256 * 3072 * 2);   // enc, per-batch SE-folded
  u16* skip_wb = (u16*)alloc((size_t)3 * 256 * 512 * 2);
  u16* skip_s  = (u16*)alloc((size_t)3 * 2 * 256 * 512 * 2);    // skip, per-batch folded
  u16* cls1_wb = (u16*)alloc((size_t)256 * 256 * 2);            // zero-padded to 256 rows
  u16* wp6     = (u16*)alloc((size_t)256 * 128 * 2);            // zero-padded to 256 rows
  float* stats = (float*)alloc(2048);
  float* sesum = (float*)alloc(2048);                           // contiguous after stats
  float* sig   = (float*)alloc(4 * 2048);                       // sig_i = sig + i*512
  u16* out0 = (u16*)alloc((size_t)M_N * 256 * 2);
  u16* out1 = (u16*)alloc((size_t)M_N * 256 * 2);
  u16* out2 = (u16*)alloc((size_t)M_N * 256 * 2);
  u16* ct   = (u16*)alloc((size_t)M_N * 256 * 2);               // conv temp; aliases out3
  u16* tb   = (u16*)alloc((size_t)M_N * 256 * 2);
  u16* xd   = (u16*)alloc((size_t)M_N * 256 * 2);
  u16* outs[4] = {out0, out1, out2, ct};
  const size_t WENC = (size_t)256 * 3072;      // elems per enc weight copy
  const size_t WSKP = (size_t)256 * 512;

  // prep
  perm2_k<<<768, 256, 0, stream>>>(enc_w, wpe);
  perm2_k<<<768, 256, 0, stream>>>(dec_w, wpe + (size_t)3 * WENC);
  cvt_k<<<1536, 256, 0, stream>>>(skip_w, skip_wb, 3 * 256 * 512);
  hipMemsetAsync(cls1_wb, 0, 256 * 256 * 2, stream);
  cvt_k<<<128, 256, 0, stream>>>(cls1_w, cls1_wb, 128 * 256);
  hipMemsetAsync(wp6, 0, 256 * 128 * 2, stream);
  cvt_k<<<32, 256, 0, stream>>>(cls2_w, wp6, 64 * 128);

  // ---- encoder block 0 ----
  hipMemsetAsync(stats, 0, 4096, stream);
  enc0_k<<<1024, 256, 0, stream>>>(verts, spirals, enc0_w, ct);
  stats2_k<<<512, 256, 0, stream>>>(ct, stats);
  bnrelu2_k<<<512, 256, 0, stream>>>(ct, stats, enc0_g, enc0_be, nullptr, nullptr, out0, sesum, 256);
  se_k<<<2, 256, 0, stream>>>(sesum, se_w1, se_w2, sig);

  // ---- encoder blocks 1..3 (SE scale folded into per-batch weights) ----
  for (int i = 1; i < 4; ++i) {
    wscale_k<<<3072, 256, 0, stream>>>(wpe + (size_t)(i - 1) * WENC, sig + (i - 1) * 512, nullptr,
                                       wpe_s + (size_t)(i - 1) * 2 * WENC, (int)WENC, 255);
    hipMemsetAsync(stats, 0, 4096, stream);
    gemm3_k<256><<<512, 512, 0, stream>>>(outs[i - 1], nullptr, 256,
                                          spirals + (size_t)i * V_N * 12, 12,
                                          wpe_s + (size_t)(i - 1) * 2 * WENC, (long)WENC,
                                          ct, nullptr, 256, stats);
    bnrelu2_k<<<512, 256, 0, stream>>>(ct, stats, enc_g + (i - 1) * 256, enc_be + (i - 1) * 256,
                                       outs[i - 1], sig + (i - 1) * 512, outs[i], sesum, 256);
    se_k<<<2, 256, 0, stream>>>(sesum, se_w1 + (size_t)i * 32 * 256,
                                se_w2 + (size_t)i * 256 * 32, sig + i * 512);
  }

  // ---- decoder blocks (decoder input SE-scale folded into skip weights at i=0) ----
  for (int i = 0; i < 3; ++i) {
    wscale_k<<<512, 256, 0, stream>>>(skip_wb + (size_t)i * WSKP, sig + (2 - i) * 512,
                                      (i == 0) ? (sig + 3 * 512) : nullptr,
                                      skip_s + (size_t)i * 2 * WSKP, (int)WSKP, 511);
    gemm3_k<256><<<512, 512, 0, stream>>>((i == 0) ? ct : xd, outs[2 - i], 256, nullptr, 2,
                                          skip_s + (size_t)i * 2 * WSKP, (long)WSKP,
                                          tb, skip_b + i * 256, 256, nullptr);       // x1 -> tb
    hipMemsetAsync(stats, 0, 4096, stream);
    gemm3_k<256><<<512, 512, 0, stream>>>(tb, nullptr, 256,
                                          spirals + (size_t)(2 - i) * V_N * 12, 12,
                                          wpe + (size_t)(3 + i) * WENC, 0,
                                          outs[2 - i], nullptr, 256, stats);          // conv -> out[2-i]
    bnrelu2_k<<<512, 256, 0, stream>>>(outs[2 - i], stats, dec_g + i * 256, dec_be + i * 256,
                                       tb, nullptr, xd, nullptr, 256);                // x -> xd
  }

  // ---- classifier ----
  hipMemsetAsync(stats, 0, 4096, stream);
  gemm3_k<256><<<512, 512, 0, stream>>>(xd, nullptr, 256, nullptr, 1,
                                        cls1_wb, 0, ct, nullptr, 128, stats);
  bnrelu2_k<<<256, 256, 0, stream>>>(ct, stats, cls1_g, cls1_be, nullptr, nullptr, ct, nullptr, 128);
  hipMemsetAsync(stats, 0, 4096, stream);
  gemm3_k<128><<<512, 512, 0, stream>>>(ct, nullptr, 128, nullptr, 1,
                                        wp6, 0, tb, nullptr, 64, stats);
  bnrelu2_k<<<128, 256, 0, stream>>>(tb, stats, cls2_g, cls2_be, nullptr, nullptr, tb, nullptr, 64);
  cls3_k<<<128, 256, 0, stream>>>(tb, cls3_w, cls3_b, (float*)d_out);
}

// Round 6
// 914.295 us; speedup vs baseline: 1.5927x; 1.2296x over previous
//
#include <hip/hip_runtime.h>

typedef unsigned short u16;
using f16x8 = __attribute__((ext_vector_type(8))) _Float16;  // 8 fp16 (4 VGPRs)
using f32x4 = __attribute__((ext_vector_type(4))) float;

#define V_N 16384
#define M_N 32768

__device__ __forceinline__ float h2f(u16 u) {
  _Float16 h; __builtin_memcpy(&h, &u, 2); return (float)h;
}
__device__ __forceinline__ u16 f2h(float f) {
  _Float16 h = (_Float16)f; u16 u; __builtin_memcpy(&u, &h, 2); return u;
}

// async global->LDS DMA, 16B per lane; LDS dest = wave-uniform base + lane*16
__device__ __forceinline__ void dma16(const u16* g, u16* l) {
  __builtin_amdgcn_global_load_lds(
      (const __attribute__((address_space(1))) void*)(const void*)g,
      (__attribute__((address_space(3))) void*)(void*)l, 16, 0, 0);
}

// ---------- prep kernels ----------
// Weight permute to FRAGMENT-MAJOR: dst[kc][col][lq][j] (kc = k>>5, lq=(k>>3)&3,
// j=k&7, k = tap*256 + c). A wave's B-fragment load is then a contiguous 1KB
// region (R5 lesson: col-major-strided fragments = 64 scattered lines/instr ->
// TA serialization was the ~118us invariant wall).
__global__ __launch_bounds__(256) void perm2_k(const float* __restrict__ w, u16* __restrict__ wp) {
  int o = blockIdx.x & 255, layer = blockIdx.x >> 8;
  int t = threadIdx.x;                       // t = input channel c
  const float* src = w + ((size_t)layer * 256 + o) * 3072;
  u16* dst = wp + (size_t)layer * 786432;    // frag-major layer base
  float2 v[6];
  #pragma unroll
  for (int q = 0; q < 6; ++q) v[q] = *(const float2*)(src + t * 12 + q * 2);
  const float* vf = (const float*)v;         // vf[m] = w[o][c=t, tap=m]
  int lo = t & 31;                           // (k&31) = lq*8+j
  #pragma unroll
  for (int m = 0; m < 12; ++m) {
    int kc = m * 8 + (t >> 5);               // k = m*256 + t
    dst[(size_t)kc * 8192 + o * 32 + lo] = f2h(vf[m]);
  }
}

// generic f32 [O][K] row-major -> frag-major fp16 [kc][256][lq][j], zero-pad col>=O
__global__ __launch_bounds__(256) void permfr_k(const float* __restrict__ src, u16* __restrict__ dst,
                                                int O, int K) {
  int i = blockIdx.x * 256 + threadIdx.x;
  if (i >= (K << 8)) return;
  int j = i & 7, lq = (i >> 3) & 3, col = (i >> 5) & 255, kc = i >> 13;
  int k = kc * 32 + lq * 8 + j;
  float v = (col < O) ? src[(size_t)col * K + k] : 0.f;
  dst[i] = f2h(v);
}

// per-batch SE-scale fold into frag-major weights: o[b][i] = w[i] * s
// k reconstructed from frag index. sel=255: enc conv (all k scaled by sig).
// sel=511: skip (k>=256 scaled by sig; k<256 by sigx if non-null, else 1).
__global__ __launch_bounds__(256) void wscale_k(const u16* __restrict__ w, const float* __restrict__ sig,
                                                const float* __restrict__ sigx,
                                                u16* __restrict__ o, int n, int sel) {
  int i = blockIdx.x * 256 + threadIdx.x;
  if (i >= n) return;
  float wv = h2f(w[i]);
  int k = (i >> 13) * 32 + ((i >> 3) & 3) * 8 + (i & 7);
  int c = k & 255;
  #pragma unroll
  for (int b = 0; b < 2; ++b) {
    float s;
    if (sel == 511 && k < 256) s = sigx ? sigx[b * 256 + c] : 1.f;
    else                       s = sig[b * 256 + c];
    o[(long)b * n + i] = f2h(wv * s);
  }
}

// ---------- encoder block 0 conv (C_in=3, K=36), f32 in -> fp16 out ----------
__global__ __launch_bounds__(256) void enc0_k(const float* __restrict__ verts, const int* __restrict__ sp,
                                              const float* __restrict__ w0, u16* __restrict__ y) {
  __shared__ float xs[32][36];
  int t = threadIdx.x;
  int r0 = blockIdx.x * 32;
  for (int s = t; s < 32 * 12; s += 256) {
    int row = s / 12, tt = s - row * 12;
    int gr = r0 + row;
    int b = gr >> 14, v = gr & (V_N - 1);
    int j = sp[tt * V_N + v];
    const float* p = verts + ((long)b * V_N + j) * 3;
    xs[row][tt]      = p[0];
    xs[row][12 + tt] = p[1];
    xs[row][24 + tt] = p[2];
  }
  __syncthreads();
  float w[36];
  #pragma unroll
  for (int k = 0; k < 36; ++k) w[k] = w0[t * 36 + k];
  for (int row = 0; row < 32; ++row) {
    float a = 0.f;
    #pragma unroll
    for (int k = 0; k < 36; ++k) a += w[k] * xs[row][k];
    y[(long)(r0 + row) * 256 + t] = f2h(a);
  }
}

// ---------- MFMA GEMM: 64M x 256N tile, 512 thr, K-phase-split + frag-major B ----------
// R5 structure (drain-barrier double-buffer, phase-split gather, 2x8KB LDS,
// 2 blocks/CU) + fragment-major B: one B-load instr = 64 lanes reading a
// contiguous 1KB block (16 sequential lines, vs 64 scattered lines before).
// Per block-stage the B slice is one contiguous 32KB region, L2-shared by all
// blocks in the same phase.
template<int CT>
__global__ __launch_bounds__(512, 4) void gemm3_k(
    const u16* __restrict__ P0, const u16* __restrict__ P1, int lda,
    const int* __restrict__ sp, int L,
    const u16* __restrict__ Wt, long wstride,
    u16* __restrict__ Yb, const float* __restrict__ bias, int Ostore,
    float* __restrict__ stats)
{
  constexpr int KC   = CT >> 5;            // k-chunks (32 elems) per tap (8 or 4)
  constexpr int PH   = (CT == 256) ? 4 : 2;// phases -> 64-elem slice always
  constexpr int KCP  = KC / PH;            // k-chunks per stage = 2
  constexpr int PROW = 64;                 // elems per row per stage (128B)
  __shared__ __align__(16) u16 lA[2][64 * PROW];   // 2 x 8KB stage buffers
  const int tid  = threadIdx.x;
  const int wave = tid >> 6, lane = tid & 63;
  const int wn = wave * 32;                // N-split-8: 32 cols per wave
  const int lr = lane & 15, lq = lane >> 4;
  // XCD-aware bijective swizzle (nwg % 8 == 0 for all call sites)
  const int nwg = gridDim.x;
  const int wg = (blockIdx.x & 7) * (nwg >> 3) + (blockIdx.x >> 3);
  const int bm = wg * 64;
  const int batch = bm >> 14;
  const int vbase = bm & (V_N - 1);
  const int qrow = lane >> 3;              // row within DMA instr (8 rows/instr)
  const int qchunk = lane & 7;             // 16B chunk within 128B slice
  const bool gat = (sp != nullptr);
  const long rowb = (long)batch * V_N;     // gather row base (rows)
  const u16* Pd1 = P1 ? P1 : P0;
  const u16* Wb = Wt + (long)batch * wstride;
  const int NS = PH * L;                   // total stages

  // frag-major B pointers: fragment (col=wn+nt*16+lr, half lq) of kchunk kc at
  // Wb + kc*8192 + col*32 + lq*8  (64 lanes of one instr -> contiguous 1KB)
  const u16* bp[2];
  #pragma unroll
  for (int nt = 0; nt < 2; ++nt)
    bp[nt] = Wb + ((long)(wn + nt * 16 + lr) * 4 + lq) * 8;

  auto load_idx = [&](int tap) -> int {
    int v = 0;
    if (gat && lane < 8) v = sp[(long)tap * V_N + vbase + wave * 8 + lane];
    return v;
  };

  // stage DMA: 64 rows x 128B slice; wave w covers rows [w*8, w*8+8), 1 instr
  auto dma_st = [&](int sb, const u16* src, int idxreg, int ph) {
    u16* wb = lA[sb] + wave * (8 * PROW);
    int rloc = wave * 8 + qrow;
    long grow;
    if (gat) grow = rowb + (long)__shfl(idxreg, qrow, 64);
    else     grow = bm + rloc;
    const u16* gp = src + grow * lda + ph * PROW + ((qchunk ^ (rloc & 7)) << 3);
    dma16(gp, wb);
  };

  auto loadB = [&](int cb, f16x8 (&tB)[KCP * 2]) {
    #pragma unroll
    for (int kp = 0; kp < KCP; ++kp)
      #pragma unroll
      for (int nt = 0; nt < 2; ++nt)
        tB[kp * 2 + nt] = *(const f16x8*)(bp[nt] + (long)(cb + kp) * 8192);
  };

  f32x4 acc[4][2];
  #pragma unroll
  for (int i = 0; i < 4; ++i)
    #pragma unroll
    for (int j = 0; j < 2; ++j) acc[i][j] = (f32x4){0.f, 0.f, 0.f, 0.f};

  auto compute_st = [&](int sb, const f16x8 (&tB)[KCP * 2]) {
    #pragma unroll
    for (int kp = 0; kp < KCP; ++kp) {
      f16x8 a[4];
      #pragma unroll
      for (int mt = 0; mt < 4; ++mt) {
        int row = mt * 16 + lr;
        a[mt] = *(const f16x8*)(&lA[sb][row * PROW + (((kp * 4 + lq) ^ (row & 7)) << 3)]);
      }
      #pragma unroll
      for (int mt = 0; mt < 4; ++mt)
        #pragma unroll
        for (int nt = 0; nt < 2; ++nt)
          acc[mt][nt] = __builtin_amdgcn_mfma_f32_16x16x32_f16(a[mt], tB[kp * 2 + nt], acc[mt][nt], 0, 0, 0);
    }
  };

  f16x8 tBc[KCP * 2], tBn[KCP * 2];

  // ---- prologue: stage 0 = (tap0, ph0) ----
  int idxC = load_idx(0);
  dma_st(0, P0, idxC, 0);
  loadB(0, tBc);
  int idxN = (gat && L > 1) ? load_idx(1) : idxC;   // tap of stage 1

  int l = 0, ph = 0;
  for (int s = 0; s < NS; ++s) {
    int ln  = (l + 1 == L) ? 0 : l + 1;             // tap of stage s+1
    int phn = (l + 1 == L) ? ph + 1 : ph;           // phase of stage s+1
    __syncthreads();                                 // drains DMA(s)
    if (s + 1 < NS) {
      const u16* srcN = (!gat && ln > 0) ? Pd1 : P0;
      dma_st((s + 1) & 1, srcN, idxN, phn);
      loadB(ln * KC + phn * KCP, tBn);
    }
    int idxF = 0;
    if (gat && s + 2 < NS) {
      int l2 = (ln + 1 == L) ? 0 : ln + 1;          // tap of stage s+2
      idxF = load_idx(l2);
    }
    compute_st(s & 1, tBc);
    #pragma unroll
    for (int i = 0; i < KCP * 2; ++i) tBc[i] = tBn[i];
    idxN = idxF;
    l = ln; ph = phn;
  }

  // epilogue: C/D layout col=lane&15, row=(lane>>4)*4+reg [guide m89]; fused stats
  #pragma unroll
  for (int nt = 0; nt < 2; ++nt) {
    int col = wn + nt * 16 + lr;
    if (col < Ostore) {
      float bv = bias ? bias[col] : 0.f;
      float s1 = 0.f, s2 = 0.f;
      #pragma unroll
      for (int mt = 0; mt < 4; ++mt) {
        #pragma unroll
        for (int rg = 0; rg < 4; ++rg) {
          int row = bm + mt * 16 + lq * 4 + rg;
          float v = acc[mt][nt][rg] + bv;
          Yb[(long)row * Ostore + col] = f2h(v);
          s1 += v; s2 += v * v;
        }
      }
      if (stats) {
        s1 += __shfl_xor(s1, 16); s1 += __shfl_xor(s1, 32);
        s2 += __shfl_xor(s2, 16); s2 += __shfl_xor(s2, 32);
        if (lq == 0) {
          atomicAdd(&stats[col], s1);
          atomicAdd(&stats[Ostore + col], s2);
        }
      }
    }
  }
}

// ---------- stats for enc0 output (O=256), vectorized ----------
__global__ __launch_bounds__(256) void stats2_k(const u16* __restrict__ y, float* __restrict__ st) {
  __shared__ float s1L[256], s2L[256];
  int tid = threadIdx.x;
  int ci = (tid & 63) * 4;
  int r0 = blockIdx.x * 64 + (tid >> 6);
  float a1[4] = {0,0,0,0}, a2[4] = {0,0,0,0};
  for (int it = 0; it < 16; ++it) {
    long i = ((long)r0 + it * 4) * 256 + ci;
    uint2 pv = *(const uint2*)(y + i);
    float v0 = h2f((u16)(pv.x & 0xffff)), v1 = h2f((u16)(pv.x >> 16));
    float v2 = h2f((u16)(pv.y & 0xffff)), v3 = h2f((u16)(pv.y >> 16));
    a1[0] += v0; a1[1] += v1; a1[2] += v2; a1[3] += v3;
    a2[0] += v0*v0; a2[1] += v1*v1; a2[2] += v2*v2; a2[3] += v3*v3;
  }
  s1L[tid] = 0.f; s2L[tid] = 0.f;
  __syncthreads();
  #pragma unroll
  for (int j = 0; j < 4; ++j) { atomicAdd(&s1L[ci + j], a1[j]); atomicAdd(&s2L[ci + j], a2[j]); }
  __syncthreads();
  atomicAdd(&st[tid], s1L[tid]);
  atomicAdd(&st[256 + tid], s2L[tid]);
}

// ---------- vectorized BN+ReLU (+fp16 residual, optional per-channel resid scale) (+SE sums) ----------
__global__ __launch_bounds__(256) void bnrelu2_k(
    const u16* __restrict__ y, const float* __restrict__ st,
    const float* __restrict__ g, const float* __restrict__ be,
    const u16* __restrict__ resid, const float* __restrict__ rscale,
    u16* __restrict__ ob, float* __restrict__ ses, int O)
{
  __shared__ float sL[256];
  int tid = threadIdx.x;
  int tpr = O >> 2;
  int rpi = 256 / tpr;
  int ci = (tid & (tpr - 1)) * 4;
  int row0 = blockIdx.x * (rpi * 16);
  int r0 = row0 + (tid / tpr);
  int b = row0 >> 14;
  float mean[4], sc[4], sh[4], rs[4];
  #pragma unroll
  for (int j = 0; j < 4; ++j) {
    int c = ci + j;
    float m = st[c] * (1.f / 32768.f);
    float var = st[O + c] * (1.f / 32768.f) - m * m;
    mean[j] = m;
    sc[j] = rsqrtf(fmaxf(var, 0.f) + 1e-5f) * g[c];
    sh[j] = be[c];
    rs[j] = rscale ? rscale[b * 256 + c] : 1.f;
  }
  float ss[4] = {0,0,0,0};
  for (int it = 0; it < 16; ++it) {
    long i = ((long)r0 + (long)it * rpi) * O + ci;
    uint2 pv = *(const uint2*)(y + i);
    float v[4];
    v[0] = fmaxf((h2f((u16)(pv.x & 0xffff)) - mean[0]) * sc[0] + sh[0], 0.f);
    v[1] = fmaxf((h2f((u16)(pv.x >> 16))    - mean[1]) * sc[1] + sh[1], 0.f);
    v[2] = fmaxf((h2f((u16)(pv.y & 0xffff)) - mean[2]) * sc[2] + sh[2], 0.f);
    v[3] = fmaxf((h2f((u16)(pv.y >> 16))    - mean[3]) * sc[3] + sh[3], 0.f);
    if (resid) {
      uint2 rv = *(const uint2*)(resid + i);
      v[0] += h2f((u16)(rv.x & 0xffff)) * rs[0]; v[1] += h2f((u16)(rv.x >> 16)) * rs[1];
      v[2] += h2f((u16)(rv.y & 0xffff)) * rs[2]; v[3] += h2f((u16)(rv.y >> 16)) * rs[3];
    }
    uint2 pk;
    pk.x = (unsigned)f2h(v[0]) | ((unsigned)f2h(v[1]) << 16);
    pk.y = (unsigned)f2h(v[2]) | ((unsigned)f2h(v[3]) << 16);
    *(uint2*)(ob + i) = pk;
    #pragma unroll
    for (int j = 0; j < 4; ++j) ss[j] += v[j];
  }
  if (ses) {
    sL[tid] = 0.f;
    __syncthreads();
    #pragma unroll
    for (int j = 0; j < 4; ++j) atomicAdd(&sL[ci + j], ss[j]);
    __syncthreads();
    atomicAdd(&ses[b * O + tid], sL[tid]);
  }
}

// ---------- SE gate ----------
__global__ void se_k(const float* __restrict__ ses, const float* __restrict__ w1,
                     const float* __restrict__ w2, float* __restrict__ sig)
{
  __shared__ float s[256];
  __shared__ float h[32];
  int b = blockIdx.x, t = threadIdx.x;
  s[t] = ses[b * 256 + t] * (1.f / 16384.f);
  __syncthreads();
  if (t < 32) {
    float a = 0.f;
    for (int c = 0; c < 256; ++c) a += w1[t * 256 + c] * s[c];
    h[t] = fmaxf(a, 0.f);
  }
  __syncthreads();
  float a = 0.f;
  #pragma unroll
  for (int r = 0; r < 32; ++r) a += w2[t * 32 + r] * h[r];
  sig[b * 256 + t] = 1.f / (1.f + expf(-a));
}

// ---------- final head ----------
__global__ __launch_bounds__(256) void cls3_k(const u16* __restrict__ h2, const float* __restrict__ w,
                                              const float* __restrict__ b, float* __restrict__ out)
{
  __shared__ float ws[64];
  int t = threadIdx.x;
  if (t < 64) ws[t] = w[t];
  __syncthreads();
  int r = blockIdx.x * 256 + t;
  const u16* p = h2 + (long)r * 64;
  float a = b[0];
  #pragma unroll
  for (int c = 0; c < 64; ++c) a += ws[c] * h2f(p[c]);
  out[r] = a;
}

extern "C" void kernel_launch(void* const* d_in, const int* in_sizes, int n_in,
                              void* d_out, int out_size, void* d_ws, size_t ws_size,
                              hipStream_t stream)
{
  (void)in_sizes; (void)n_in; (void)out_size; (void)ws_size;
  const float* verts   = (const float*)d_in[0];
  const int*   spirals = (const int*)d_in[1];
  const float* enc0_w  = (const float*)d_in[2];
  const float* enc0_g  = (const float*)d_in[4];
  const float* enc0_be = (const float*)d_in[5];
  const float* enc_w   = (const float*)d_in[6];
  const float* enc_g   = (const float*)d_in[8];
  const float* enc_be  = (const float*)d_in[9];
  const float* se_w1   = (const float*)d_in[10];
  const float* se_w2   = (const float*)d_in[11];
  const float* skip_w  = (const float*)d_in[12];
  const float* skip_b  = (const float*)d_in[13];
  const float* dec_w   = (const float*)d_in[14];
  const float* dec_g   = (const float*)d_in[16];
  const float* dec_be  = (const float*)d_in[17];
  const float* cls1_w  = (const float*)d_in[18];
  const float* cls1_g  = (const float*)d_in[20];
  const float* cls1_be = (const float*)d_in[21];
  const float* cls2_w  = (const float*)d_in[22];
  const float* cls2_g  = (const float*)d_in[24];
  const float* cls2_be = (const float*)d_in[25];
  const float* cls3_w  = (const float*)d_in[26];
  const float* cls3_b  = (const float*)d_in[27];

  // --- workspace (~118 MB) ---
  char* p = (char*)d_ws;
  auto alloc = [&](size_t n) { char* q = p; p += (n + 255) & ~(size_t)255; return q; };
  u16* wpe     = (u16*)alloc((size_t)6 * 256 * 3072 * 2);       // 6 permuted conv weights
  u16* wpe_s   = (u16*)alloc((size_t)3 * 2 * 256 * 3072 * 2);   // enc, per-batch SE-folded
  u16* skip_wb = (u16*)alloc((size_t)3 * 256 * 512 * 2);
  u16* skip_s  = (u16*)alloc((size_t)3 * 2 * 256 * 512 * 2);    // skip, per-batch folded
  u16* cls1_wb = (u16*)alloc((size_t)256 * 256 * 2);            // zero-padded to 256 cols
  u16* wp6     = (u16*)alloc((size_t)256 * 128 * 2);            // zero-padded to 256 cols
  float* stats = (float*)alloc(2048);
  float* sesum = (float*)alloc(2048);                           // contiguous after stats
  float* sig   = (float*)alloc(4 * 2048);                       // sig_i = sig + i*512
  u16* out0 = (u16*)alloc((size_t)M_N * 256 * 2);
  u16* out1 = (u16*)alloc((size_t)M_N * 256 * 2);
  u16* out2 = (u16*)alloc((size_t)M_N * 256 * 2);
  u16* ct   = (u16*)alloc((size_t)M_N * 256 * 2);               // conv temp; aliases out3
  u16* tb   = (u16*)alloc((size_t)M_N * 256 * 2);
  u16* xd   = (u16*)alloc((size_t)M_N * 256 * 2);
  u16* outs[4] = {out0, out1, out2, ct};
  const size_t WENC = (size_t)256 * 3072;      // elems per enc weight copy
  const size_t WSKP = (size_t)256 * 512;

  // prep (all weights -> fragment-major)
  perm2_k<<<768, 256, 0, stream>>>(enc_w, wpe);
  perm2_k<<<768, 256, 0, stream>>>(dec_w, wpe + (size_t)3 * WENC);
  for (int s = 0; s < 3; ++s)
    permfr_k<<<512, 256, 0, stream>>>(skip_w + (size_t)s * 256 * 512,
                                      skip_wb + (size_t)s * WSKP, 256, 512);
  permfr_k<<<256, 256, 0, stream>>>(cls1_w, cls1_wb, 128, 256);
  permfr_k<<<128, 256, 0, stream>>>(cls2_w, wp6, 64, 128);

  // ---- encoder block 0 ----
  hipMemsetAsync(stats, 0, 4096, stream);
  enc0_k<<<1024, 256, 0, stream>>>(verts, spirals, enc0_w, ct);
  stats2_k<<<512, 256, 0, stream>>>(ct, stats);
  bnrelu2_k<<<512, 256, 0, stream>>>(ct, stats, enc0_g, enc0_be, nullptr, nullptr, out0, sesum, 256);
  se_k<<<2, 256, 0, stream>>>(sesum, se_w1, se_w2, sig);

  // ---- encoder blocks 1..3 (SE scale folded into per-batch weights) ----
  for (int i = 1; i < 4; ++i) {
    wscale_k<<<3072, 256, 0, stream>>>(wpe + (size_t)(i - 1) * WENC, sig + (i - 1) * 512, nullptr,
                                       wpe_s + (size_t)(i - 1) * 2 * WENC, (int)WENC, 255);
    hipMemsetAsync(stats, 0, 4096, stream);
    gemm3_k<256><<<512, 512, 0, stream>>>(outs[i - 1], nullptr, 256,
                                          spirals + (size_t)i * V_N * 12, 12,
                                          wpe_s + (size_t)(i - 1) * 2 * WENC, (long)WENC,
                                          ct, nullptr, 256, stats);
    bnrelu2_k<<<512, 256, 0, stream>>>(ct, stats, enc_g + (i - 1) * 256, enc_be + (i - 1) * 256,
                                       outs[i - 1], sig + (i - 1) * 512, outs[i], sesum, 256);
    se_k<<<2, 256, 0, stream>>>(sesum, se_w1 + (size_t)i * 32 * 256,
                                se_w2 + (size_t)i * 256 * 32, sig + i * 512);
  }

  // ---- decoder blocks (decoder input SE-scale folded into skip weights at i=0) ----
  for (int i = 0; i < 3; ++i) {
    wscale_k<<<512, 256, 0, stream>>>(skip_wb + (size_t)i * WSKP, sig + (2 - i) * 512,
                                      (i == 0) ? (sig + 3 * 512) : nullptr,
                                      skip_s + (size_t)i * 2 * WSKP, (int)WSKP, 511);
    gemm3_k<256><<<512, 512, 0, stream>>>((i == 0) ? ct : xd, outs[2 - i], 256, nullptr, 2,
                                          skip_s + (size_t)i * 2 * WSKP, (long)WSKP,
                                          tb, skip_b + i * 256, 256, nullptr);       // x1 -> tb
    hipMemsetAsync(stats, 0, 4096, stream);
    gemm3_k<256><<<512, 512, 0, stream>>>(tb, nullptr, 256,
                                          spirals + (size_t)(2 - i) * V_N * 12, 12,
                                          wpe + (size_t)(3 + i) * WENC, 0,
                                          outs[2 - i], nullptr, 256, stats);          // conv -> out[2-i]
    bnrelu2_k<<<512, 256, 0, stream>>>(outs[2 - i], stats, dec_g + i * 256, dec_be + i * 256,
                                       tb, nullptr, xd, nullptr, 256);                // x -> xd
  }

  // ---- classifier ----
  hipMemsetAsync(stats, 0, 4096, stream);
  gemm3_k<256><<<512, 512, 0, stream>>>(xd, nullptr, 256, nullptr, 1,
                                        cls1_wb, 0, ct, nullptr, 128, stats);
  bnrelu2_k<<<256, 256, 0, stream>>>(ct, stats, cls1_g, cls1_be, nullptr, nullptr, ct, nullptr, 128);
  hipMemsetAsync(stats, 0, 4096, stream);
  gemm3_k<128><<<512, 512, 0, stream>>>(ct, nullptr, 128, nullptr, 1,
                                        wp6, 0, tb, nullptr, 64, stats);
  bnrelu2_k<<<128, 256, 0, stream>>>(tb, stats, cls2_g, cls2_be, nullptr, nullptr, tb, nullptr, 64);
  cls3_k<<<128, 256, 0, stream>>>(tb, cls3_w, cls3_b, (float*)d_out);
}

// Round 7
// 884.505 us; speedup vs baseline: 1.6464x; 1.0337x over previous
//
#include <hip/hip_runtime.h>

typedef unsigned short u16;
using f16x8 = __attribute__((ext_vector_type(8))) _Float16;  // 8 fp16 (4 VGPRs)
using f32x4 = __attribute__((ext_vector_type(4))) float;

#define V_N 16384
#define M_N 32768

__device__ __forceinline__ float h2f(u16 u) {
  _Float16 h; __builtin_memcpy(&h, &u, 2); return (float)h;
}
__device__ __forceinline__ u16 f2h(float f) {
  _Float16 h = (_Float16)f; u16 u; __builtin_memcpy(&u, &h, 2); return u;
}

// async global->LDS DMA, 16B per lane; LDS dest = wave-uniform base + lane*16
__device__ __forceinline__ void dma16(const u16* g, u16* l) {
  __builtin_amdgcn_global_load_lds(
      (const __attribute__((address_space(1))) void*)(const void*)g,
      (__attribute__((address_space(3))) void*)(void*)l, 16, 0, 0);
}

// ---------- prep kernels ----------
// Weight permute to FRAGMENT-MAJOR: dst[kc][col][lq][j] (kc = k>>5, lq=(k>>3)&3,
// j=k&7, k = tap*256 + c). A wave's B-fragment load is then a contiguous 1KB
// region (R5 lesson: col-major-strided fragments = 64 scattered lines/instr ->
// TA serialization was the ~118us invariant wall).
__global__ __launch_bounds__(256) void perm2_k(const float* __restrict__ w, u16* __restrict__ wp) {
  int o = blockIdx.x & 255, layer = blockIdx.x >> 8;
  int t = threadIdx.x;                       // t = input channel c
  const float* src = w + ((size_t)layer * 256 + o) * 3072;
  u16* dst = wp + (size_t)layer * 786432;    // frag-major layer base
  float2 v[6];
  #pragma unroll
  for (int q = 0; q < 6; ++q) v[q] = *(const float2*)(src + t * 12 + q * 2);
  const float* vf = (const float*)v;         // vf[m] = w[o][c=t, tap=m]
  int lo = t & 31;                           // (k&31) = lq*8+j
  #pragma unroll
  for (int m = 0; m < 12; ++m) {
    int kc = m * 8 + (t >> 5);               // k = m*256 + t
    dst[(size_t)kc * 8192 + o * 32 + lo] = f2h(vf[m]);
  }
}

// generic f32 [O][K] row-major -> frag-major fp16 [kc][256][lq][j], zero-pad col>=O
__global__ __launch_bounds__(256) void permfr_k(const float* __restrict__ src, u16* __restrict__ dst,
                                                int O, int K) {
  int i = blockIdx.x * 256 + threadIdx.x;
  if (i >= (K << 8)) return;
  int j = i & 7, lq = (i >> 3) & 3, col = (i >> 5) & 255, kc = i >> 13;
  int k = kc * 32 + lq * 8 + j;
  float v = (col < O) ? src[(size_t)col * K + k] : 0.f;
  dst[i] = f2h(v);
}

// per-batch SE-scale fold into frag-major weights: o[b][i] = w[i] * s
// k reconstructed from frag index. sel=255: enc conv (all k scaled by sig).
// sel=511: skip (k>=256 scaled by sig; k<256 by sigx if non-null, else 1).
__global__ __launch_bounds__(256) void wscale_k(const u16* __restrict__ w, const float* __restrict__ sig,
                                                const float* __restrict__ sigx,
                                                u16* __restrict__ o, int n, int sel) {
  int i = blockIdx.x * 256 + threadIdx.x;
  if (i >= n) return;
  float wv = h2f(w[i]);
  int k = (i >> 13) * 32 + ((i >> 3) & 3) * 8 + (i & 7);
  int c = k & 255;
  #pragma unroll
  for (int b = 0; b < 2; ++b) {
    float s;
    if (sel == 511 && k < 256) s = sigx ? sigx[b * 256 + c] : 1.f;
    else                       s = sig[b * 256 + c];
    o[(long)b * n + i] = f2h(wv * s);
  }
}

// ---------- encoder block 0 conv (C_in=3, K=36), f32 in -> fp16 out ----------
__global__ __launch_bounds__(256) void enc0_k(const float* __restrict__ verts, const int* __restrict__ sp,
                                              const float* __restrict__ w0, u16* __restrict__ y) {
  __shared__ float xs[32][36];
  int t = threadIdx.x;
  int r0 = blockIdx.x * 32;
  for (int s = t; s < 32 * 12; s += 256) {
    int row = s / 12, tt = s - row * 12;
    int gr = r0 + row;
    int b = gr >> 14, v = gr & (V_N - 1);
    int j = sp[tt * V_N + v];
    const float* p = verts + ((long)b * V_N + j) * 3;
    xs[row][tt]      = p[0];
    xs[row][12 + tt] = p[1];
    xs[row][24 + tt] = p[2];
  }
  __syncthreads();
  float w[36];
  #pragma unroll
  for (int k = 0; k < 36; ++k) w[k] = w0[t * 36 + k];
  for (int row = 0; row < 32; ++row) {
    float a = 0.f;
    #pragma unroll
    for (int k = 0; k < 36; ++k) a += w[k] * xs[row][k];
    y[(long)(r0 + row) * 256 + t] = f2h(a);
  }
}

// ---------- MFMA GEMM: 64M x 256N, K-phase-split, frag-major B, depth-2 DMA ----------
// R6 structure + counted-vmcnt depth-2 gather pipeline:
//  - 3 x 8KB LDS stage buffers; dma(s+2) issued at stage s -> ~2 stages of cover.
//  - per-stage vmem issue order (pinned by sched_barrier): loadB(s+1)[4], idx[<=1],
//    dma(s+2)[1], then pure-LDS/MFMA compute(s).
//  - LEDGER (in-order vmcnt): at wait(s), #ops younger than dma(s) =
//    loadB(s)[4] (+idx) + dma(s+1) >= 5 in every stage of every call site
//    (exactly 5 at s=NS-2 and in non-gather kernels) -> vmcnt(5) always retires
//    dma(s); dma(s+1) is among the 5 youngest -> always kept. Last stage: vmcnt(0).
//  - compiler auto-waits for tB/idx consumption retire only ops issued BEFORE the
//    in-flight dmas, never the dmas themselves.
//  - buffer reuse: dma(s+2) targets buf((s+2)%3), last read by compute(s-1) which
//    precedes barrier(s) in program order on every wave -> safe.
//  - B ping-pong in two statically-named register sets (tA/tB) + unroll-2
//    (NS = PH*L always even) -> no per-stage register copies (rule #20).
template<int CT>
__global__ __launch_bounds__(512, 4) void gemm3_k(
    const u16* __restrict__ P0, const u16* __restrict__ P1, int lda,
    const int* __restrict__ sp, int L,
    const u16* __restrict__ Wt, long wstride,
    u16* __restrict__ Yb, const float* __restrict__ bias, int Ostore,
    float* __restrict__ stats)
{
  constexpr int KC   = CT >> 5;            // k-chunks (32 elems) per tap (8 or 4)
  constexpr int PH   = (CT == 256) ? 4 : 2;// phases -> 64-elem slice always
  constexpr int KCP  = KC / PH;            // k-chunks per stage = 2
  constexpr int PROW = 64;                 // elems per row per stage (128B)
  constexpr int BUFE = 64 * PROW;          // 8KB buffer (u16 elems)
  __shared__ __align__(16) u16 lA[3 * BUFE];   // 3 stage buffers
  const int tid  = threadIdx.x;
  const int wave = tid >> 6, lane = tid & 63;
  const int wn = wave * 32;                // N-split-8: 32 cols per wave
  const int lr = lane & 15, lq = lane >> 4;
  // XCD-aware bijective swizzle (nwg % 8 == 0 for all call sites)
  const int nwg = gridDim.x;
  const int wg = (blockIdx.x & 7) * (nwg >> 3) + (blockIdx.x >> 3);
  const int bm = wg * 64;
  const int batch = bm >> 14;
  const int vbase = bm & (V_N - 1);
  const int qrow = lane >> 3;              // row within DMA instr (8 rows/instr)
  const int qchunk = lane & 7;             // 16B chunk within 128B slice
  const bool gat = (sp != nullptr);
  const long rowb = (long)batch * V_N;     // gather row base (rows)
  const u16* Pd1 = P1 ? P1 : P0;
  const u16* Wb = Wt + (long)batch * wstride;
  const int NS = PH * L;                   // total stages (even)

  // frag-major B pointers: fragment (col=wn+nt*16+lr, half lq) of kchunk kc at
  // Wb + kc*8192 + col*32 + lq*8  (64 lanes of one instr -> contiguous 1KB)
  const u16* bp[2];
  #pragma unroll
  for (int nt = 0; nt < 2; ++nt)
    bp[nt] = Wb + ((long)(wn + nt * 16 + lr) * 4 + lq) * 8;

  auto load_idx = [&](int tap) -> int {
    int v = 0;
    if (gat && lane < 8) v = sp[(long)tap * V_N + vbase + wave * 8 + lane];
    return v;
  };

  // stage DMA: 64 rows x 128B slice; wave w covers rows [w*8, w*8+8), 1 instr
  auto dma_st = [&](u16* buf, const u16* src, int idxreg, int ph) {
    u16* wb = buf + wave * (8 * PROW);
    int rloc = wave * 8 + qrow;
    long grow;
    if (gat) grow = rowb + (long)__shfl(idxreg, qrow, 64);
    else     grow = bm + rloc;
    const u16* gp = src + grow * lda + ph * PROW + ((qchunk ^ (rloc & 7)) << 3);
    dma16(gp, wb);
  };

  auto loadB = [&](int cb, f16x8 (&tB)[KCP * 2]) {
    #pragma unroll
    for (int kp = 0; kp < KCP; ++kp)
      #pragma unroll
      for (int nt = 0; nt < 2; ++nt)
        tB[kp * 2 + nt] = *(const f16x8*)(bp[nt] + (long)(cb + kp) * 8192);
  };

  f32x4 acc[4][2];
  #pragma unroll
  for (int i = 0; i < 4; ++i)
    #pragma unroll
    for (int j = 0; j < 2; ++j) acc[i][j] = (f32x4){0.f, 0.f, 0.f, 0.f};

  auto compute_st = [&](const u16* buf, const f16x8 (&tB)[KCP * 2]) {
    #pragma unroll
    for (int kp = 0; kp < KCP; ++kp) {
      f16x8 a[4];
      #pragma unroll
      for (int mt = 0; mt < 4; ++mt) {
        int row = mt * 16 + lr;
        a[mt] = *(const f16x8*)(&buf[row * PROW + (((kp * 4 + lq) ^ (row & 7)) << 3)]);
      }
      #pragma unroll
      for (int mt = 0; mt < 4; ++mt)
        #pragma unroll
        for (int nt = 0; nt < 2; ++nt)
          acc[mt][nt] = __builtin_amdgcn_mfma_f32_16x16x32_f16(a[mt], tB[kp * 2 + nt], acc[mt][nt], 0, 0, 0);
    }
  };

  f16x8 tA[KCP * 2], tB2[KCP * 2];

  // rolling stage descriptors: (lB,phB)=stage s+1, (lD,phD)=stage s+2, lI=tap(s+3)
  auto adv = [&](int& l, int& ph) { if (++l == L) { l = 0; ++ph; } };
  int lB = 0, phB = 0; adv(lB, phB);
  int lD = lB, phD = phB; adv(lD, phD);
  int lI = lD; { int pT = phD; int lT = lI; adv(lT, pT); lI = lT; }
  int idxN;   // idx for the dma issued at the CURRENT stage (stage s -> dma(s+2))

  // ---- prologue: idx(tap0,tap1,tap2); dma(0); dma(1); loadB(0) ----
  {
    int i0 = load_idx(0);
    int i1 = load_idx(lB);
    idxN = load_idx(lD);
    dma_st(lA, P0, i0, 0);
    if (NS > 1) {
      const u16* s1 = (!gat && lB > 0) ? Pd1 : P0;
      dma_st(lA + BUFE, s1, i1, phB);
    }
    __builtin_amdgcn_sched_barrier(0);
    loadB(0, tA);
    __builtin_amdgcn_sched_barrier(0);
  }

  auto stage = [&](int s, f16x8 (&tCur)[KCP * 2], f16x8 (&tNxt)[KCP * 2]) {
    if (s + 1 < NS) asm volatile("s_waitcnt vmcnt(5)" ::: "memory");
    else            asm volatile("s_waitcnt vmcnt(0)" ::: "memory");
    asm volatile("s_waitcnt lgkmcnt(0)" ::: "memory");
    __builtin_amdgcn_s_barrier();
    __builtin_amdgcn_sched_barrier(0);
    if (s + 1 < NS) loadB(lB * KC + phB * KCP, tNxt);
    __builtin_amdgcn_sched_barrier(0);
    int idxT = 0;
    if (gat && s + 3 < NS) idxT = load_idx(lI);
    if (s + 2 < NS) {
      const u16* srcD = (!gat && lD > 0) ? Pd1 : P0;
      dma_st(lA + ((s + 2) % 3) * BUFE, srcD, idxN, phD);
    }
    __builtin_amdgcn_sched_barrier(0);
    compute_st(lA + (s % 3) * BUFE, tCur);
    adv(lB, phB); adv(lD, phD); if (++lI == L) lI = 0;
    idxN = idxT;
  };

  for (int s = 0; s < NS; s += 2) {
    stage(s, tA, tB2);
    stage(s + 1, tB2, tA);
  }

  // epilogue: C/D layout col=lane&15, row=(lane>>4)*4+reg [guide m89]; fused stats
  #pragma unroll
  for (int nt = 0; nt < 2; ++nt) {
    int col = wn + nt * 16 + lr;
    if (col < Ostore) {
      float bv = bias ? bias[col] : 0.f;
      float s1 = 0.f, s2 = 0.f;
      #pragma unroll
      for (int mt = 0; mt < 4; ++mt) {
        #pragma unroll
        for (int rg = 0; rg < 4; ++rg) {
          int row = bm + mt * 16 + lq * 4 + rg;
          float v = acc[mt][nt][rg] + bv;
          Yb[(long)row * Ostore + col] = f2h(v);
          s1 += v; s2 += v * v;
        }
      }
      if (stats) {
        s1 += __shfl_xor(s1, 16); s1 += __shfl_xor(s1, 32);
        s2 += __shfl_xor(s2, 16); s2 += __shfl_xor(s2, 32);
        if (lq == 0) {
          atomicAdd(&stats[col], s1);
          atomicAdd(&stats[Ostore + col], s2);
        }
      }
    }
  }
}

// ---------- stats for enc0 output (O=256), vectorized ----------
__global__ __launch_bounds__(256) void stats2_k(const u16* __restrict__ y, float* __restrict__ st) {
  __shared__ float s1L[256], s2L[256];
  int tid = threadIdx.x;
  int ci = (tid & 63) * 4;
  int r0 = blockIdx.x * 64 + (tid >> 6);
  float a1[4] = {0,0,0,0}, a2[4] = {0,0,0,0};
  for (int it = 0; it < 16; ++it) {
    long i = ((long)r0 + it * 4) * 256 + ci;
    uint2 pv = *(const uint2*)(y + i);
    float v0 = h2f((u16)(pv.x & 0xffff)), v1 = h2f((u16)(pv.x >> 16));
    float v2 = h2f((u16)(pv.y & 0xffff)), v3 = h2f((u16)(pv.y >> 16));
    a1[0] += v0; a1[1] += v1; a1[2] += v2; a1[3] += v3;
    a2[0] += v0*v0; a2[1] += v1*v1; a2[2] += v2*v2; a2[3] += v3*v3;
  }
  s1L[tid] = 0.f; s2L[tid] = 0.f;
  __syncthreads();
  #pragma unroll
  for (int j = 0; j < 4; ++j) { atomicAdd(&s1L[ci + j], a1[j]); atomicAdd(&s2L[ci + j], a2[j]); }
  __syncthreads();
  atomicAdd(&st[tid], s1L[tid]);
  atomicAdd(&st[256 + tid], s2L[tid]);
}

// ---------- vectorized BN+ReLU (+fp16 residual, optional per-channel resid scale) (+SE sums) ----------
__global__ __launch_bounds__(256) void bnrelu2_k(
    const u16* __restrict__ y, const float* __restrict__ st,
    const float* __restrict__ g, const float* __restrict__ be,
    const u16* __restrict__ resid, const float* __restrict__ rscale,
    u16* __restrict__ ob, float* __restrict__ ses, int O)
{
  __shared__ float sL[256];
  int tid = threadIdx.x;
  int tpr = O >> 2;
  int rpi = 256 / tpr;
  int ci = (tid & (tpr - 1)) * 4;
  int row0 = blockIdx.x * (rpi * 16);
  int r0 = row0 + (tid / tpr);
  int b = row0 >> 14;
  float mean[4], sc[4], sh[4], rs[4];
  #pragma unroll
  for (int j = 0; j < 4; ++j) {
    int c = ci + j;
    float m = st[c] * (1.f / 32768.f);
    float var = st[O + c] * (1.f / 32768.f) - m * m;
    mean[j] = m;
    sc[j] = rsqrtf(fmaxf(var, 0.f) + 1e-5f) * g[c];
    sh[j] = be[c];
    rs[j] = rscale ? rscale[b * 256 + c] : 1.f;
  }
  float ss[4] = {0,0,0,0};
  for (int it = 0; it < 16; ++it) {
    long i = ((long)r0 + (long)it * rpi) * O + ci;
    uint2 pv = *(const uint2*)(y + i);
    float v[4];
    v[0] = fmaxf((h2f((u16)(pv.x & 0xffff)) - mean[0]) * sc[0] + sh[0], 0.f);
    v[1] = fmaxf((h2f((u16)(pv.x >> 16))    - mean[1]) * sc[1] + sh[1], 0.f);
    v[2] = fmaxf((h2f((u16)(pv.y & 0xffff)) - mean[2]) * sc[2] + sh[2], 0.f);
    v[3] = fmaxf((h2f((u16)(pv.y >> 16))    - mean[3]) * sc[3] + sh[3], 0.f);
    if (resid) {
      uint2 rv = *(const uint2*)(resid + i);
      v[0] += h2f((u16)(rv.x & 0xffff)) * rs[0]; v[1] += h2f((u16)(rv.x >> 16)) * rs[1];
      v[2] += h2f((u16)(rv.y & 0xffff)) * rs[2]; v[3] += h2f((u16)(rv.y >> 16)) * rs[3];
    }
    uint2 pk;
    pk.x = (unsigned)f2h(v[0]) | ((unsigned)f2h(v[1]) << 16);
    pk.y = (unsigned)f2h(v[2]) | ((unsigned)f2h(v[3]) << 16);
    *(uint2*)(ob + i) = pk;
    #pragma unroll
    for (int j = 0; j < 4; ++j) ss[j] += v[j];
  }
  if (ses) {
    sL[tid] = 0.f;
    __syncthreads();
    #pragma unroll
    for (int j = 0; j < 4; ++j) atomicAdd(&sL[ci + j], ss[j]);
    __syncthreads();
    atomicAdd(&ses[b * O + tid], sL[tid]);
  }
}

// ---------- SE gate ----------
__global__ void se_k(const float* __restrict__ ses, const float* __restrict__ w1,
                     const float* __restrict__ w2, float* __restrict__ sig)
{
  __shared__ float s[256];
  __shared__ float h[32];
  int b = blockIdx.x, t = threadIdx.x;
  s[t] = ses[b * 256 + t] * (1.f / 16384.f);
  __syncthreads();
  if (t < 32) {
    float a = 0.f;
    for (int c = 0; c < 256; ++c) a += w1[t * 256 + c] * s[c];
    h[t] = fmaxf(a, 0.f);
  }
  __syncthreads();
  float a = 0.f;
  #pragma unroll
  for (int r = 0; r < 32; ++r) a += w2[t * 32 + r] * h[r];
  sig[b * 256 + t] = 1.f / (1.f + expf(-a));
}

// ---------- final head ----------
__global__ __launch_bounds__(256) void cls3_k(const u16* __restrict__ h2, const float* __restrict__ w,
                                              const float* __restrict__ b, float* __restrict__ out)
{
  __shared__ float ws[64];
  int t = threadIdx.x;
  if (t < 64) ws[t] = w[t];
  __syncthreads();
  int r = blockIdx.x * 256 + t;
  const u16* p = h2 + (long)r * 64;
  float a = b[0];
  #pragma unroll
  for (int c = 0; c < 64; ++c) a += ws[c] * h2f(p[c]);
  out[r] = a;
}

extern "C" void kernel_launch(void* const* d_in, const int* in_sizes, int n_in,
                              void* d_out, int out_size, void* d_ws, size_t ws_size,
                              hipStream_t stream)
{
  (void)in_sizes; (void)n_in; (void)out_size; (void)ws_size;
  const float* verts   = (const float*)d_in[0];
  const int*   spirals = (const int*)d_in[1];
  const float* enc0_w  = (const float*)d_in[2];
  const float* enc0_g  = (const float*)d_in[4];
  const float* enc0_be = (const float*)d_in[5];
  const float* enc_w   = (const float*)d_in[6];
  const float* enc_g   = (const float*)d_in[8];
  const float* enc_be  = (const float*)d_in[9];
  const float* se_w1   = (const float*)d_in[10];
  const float* se_w2   = (const float*)d_in[11];
  const float* skip_w  = (const float*)d_in[12];
  const float* skip_b  = (const float*)d_in[13];
  const float* dec_w   = (const float*)d_in[14];
  const float* dec_g   = (const float*)d_in[16];
  const float* dec_be  = (const float*)d_in[17];
  const float* cls1_w  = (const float*)d_in[18];
  const float* cls1_g  = (const float*)d_in[20];
  const float* cls1_be = (const float*)d_in[21];
  const float* cls2_w  = (const float*)d_in[22];
  const float* cls2_g  = (const float*)d_in[24];
  const float* cls2_be = (const float*)d_in[25];
  const float* cls3_w  = (const float*)d_in[26];
  const float* cls3_b  = (const float*)d_in[27];

  // --- workspace (~118 MB) ---
  char* p = (char*)d_ws;
  auto alloc = [&](size_t n) { char* q = p; p += (n + 255) & ~(size_t)255; return q; };
  u16* wpe     = (u16*)alloc((size_t)6 * 256 * 3072 * 2);       // 6 permuted conv weights
  u16* wpe_s   = (u16*)alloc((size_t)3 * 2 * 256 * 3072 * 2);   // enc, per-batch SE-folded
  u16* skip_wb = (u16*)alloc((size_t)3 * 256 * 512 * 2);
  u16* skip_s  = (u16*)alloc((size_t)3 * 2 * 256 * 512 * 2);    // skip, per-batch folded
  u16* cls1_wb = (u16*)alloc((size_t)256 * 256 * 2);            // zero-padded to 256 cols
  u16* wp6     = (u16*)alloc((size_t)256 * 128 * 2);            // zero-padded to 256 cols
  float* stats = (float*)alloc(2048);
  float* sesum = (float*)alloc(2048);                           // contiguous after stats
  float* sig   = (float*)alloc(4 * 2048);                       // sig_i = sig + i*512
  u16* out0 = (u16*)alloc((size_t)M_N * 256 * 2);
  u16* out1 = (u16*)alloc((size_t)M_N * 256 * 2);
  u16* out2 = (u16*)alloc((size_t)M_N * 256 * 2);
  u16* ct   = (u16*)alloc((size_t)M_N * 256 * 2);               // conv temp; aliases out3
  u16* tb   = (u16*)alloc((size_t)M_N * 256 * 2);
  u16* xd   = (u16*)alloc((size_t)M_N * 256 * 2);
  u16* outs[4] = {out0, out1, out2, ct};
  const size_t WENC = (size_t)256 * 3072;      // elems per enc weight copy
  const size_t WSKP = (size_t)256 * 512;

  // prep (all weights -> fragment-major)
  perm2_k<<<768, 256, 0, stream>>>(enc_w, wpe);
  perm2_k<<<768, 256, 0, stream>>>(dec_w, wpe + (size_t)3 * WENC);
  for (int s = 0; s < 3; ++s)
    permfr_k<<<512, 256, 0, stream>>>(skip_w + (size_t)s * 256 * 512,
                                      skip_wb + (size_t)s * WSKP, 256, 512);
  permfr_k<<<256, 256, 0, stream>>>(cls1_w, cls1_wb, 128, 256);
  permfr_k<<<128, 256, 0, stream>>>(cls2_w, wp6, 64, 128);

  // ---- encoder block 0 ----
  hipMemsetAsync(stats, 0, 4096, stream);
  enc0_k<<<1024, 256, 0, stream>>>(verts, spirals, enc0_w, ct);
  stats2_k<<<512, 256, 0, stream>>>(ct, stats);
  bnrelu2_k<<<512, 256, 0, stream>>>(ct, stats, enc0_g, enc0_be, nullptr, nullptr, out0, sesum, 256);
  se_k<<<2, 256, 0, stream>>>(sesum, se_w1, se_w2, sig);

  // ---- encoder blocks 1..3 (SE scale folded into per-batch weights) ----
  for (int i = 1; i < 4; ++i) {
    wscale_k<<<3072, 256, 0, stream>>>(wpe + (size_t)(i - 1) * WENC, sig + (i - 1) * 512, nullptr,
                                       wpe_s + (size_t)(i - 1) * 2 * WENC, (int)WENC, 255);
    hipMemsetAsync(stats, 0, 4096, stream);
    gemm3_k<256><<<512, 512, 0, stream>>>(outs[i - 1], nullptr, 256,
                                          spirals + (size_t)i * V_N * 12, 12,
                                          wpe_s + (size_t)(i - 1) * 2 * WENC, (long)WENC,
                                          ct, nullptr, 256, stats);
    bnrelu2_k<<<512, 256, 0, stream>>>(ct, stats, enc_g + (i - 1) * 256, enc_be + (i - 1) * 256,
                                       outs[i - 1], sig + (i - 1) * 512, outs[i], sesum, 256);
    se_k<<<2, 256, 0, stream>>>(sesum, se_w1 + (size_t)i * 32 * 256,
                                se_w2 + (size_t)i * 256 * 32, sig + i * 512);
  }

  // ---- decoder blocks (decoder input SE-scale folded into skip weights at i=0) ----
  for (int i = 0; i < 3; ++i) {
    wscale_k<<<512, 256, 0, stream>>>(skip_wb + (size_t)i * WSKP, sig + (2 - i) * 512,
                                      (i == 0) ? (sig + 3 * 512) : nullptr,
                                      skip_s + (size_t)i * 2 * WSKP, (int)WSKP, 511);
    gemm3_k<256><<<512, 512, 0, stream>>>((i == 0) ? ct : xd, outs[2 - i], 256, nullptr, 2,
                                          skip_s + (size_t)i * 2 * WSKP, (long)WSKP,
                                          tb, skip_b + i * 256, 256, nullptr);       // x1 -> tb
    hipMemsetAsync(stats, 0, 4096, stream);
    gemm3_k<256><<<512, 512, 0, stream>>>(tb, nullptr, 256,
                                          spirals + (size_t)(2 - i) * V_N * 12, 12,
                                          wpe + (size_t)(3 + i) * WENC, 0,
                                          outs[2 - i], nullptr, 256, stats);          // conv -> out[2-i]
    bnrelu2_k<<<512, 256, 0, stream>>>(outs[2 - i], stats, dec_g + i * 256, dec_be + i * 256,
                                       tb, nullptr, xd, nullptr, 256);                // x -> xd
  }

  // ---- classifier ----
  hipMemsetAsync(stats, 0, 4096, stream);
  gemm3_k<256><<<512, 512, 0, stream>>>(xd, nullptr, 256, nullptr, 1,
                                        cls1_wb, 0, ct, nullptr, 128, stats);
  bnrelu2_k<<<256, 256, 0, stream>>>(ct, stats, cls1_g, cls1_be, nullptr, nullptr, ct, nullptr, 128);
  hipMemsetAsync(stats, 0, 4096, stream);
  gemm3_k<128><<<512, 512, 0, stream>>>(ct, nullptr, 128, nullptr, 1,
                                        wp6, 0, tb, nullptr, 64, stats);
  bnrelu2_k<<<128, 256, 0, stream>>>(tb, stats, cls2_g, cls2_be, nullptr, nullptr, tb, nullptr, 64);
  cls3_k<<<128, 256, 0, stream>>>(tb, cls3_w, cls3_b, (float*)d_out);
}